// Round 6
// baseline (530.273 us; speedup 1.0000x reference)
//
#include <hip/hip_runtime.h>
#include <math.h>

#define SEQL   45000
#define NBAT   2
#define CCH    32
#define NSEL   512
#define NHEAD  4
#define DKD    32
#define HDD    128
#define MLPD   512
#define CDCAP  2048
#define TKB    32     // scan slices per (b,channel)
#define ETB    176    // etab blocks = ceil(45000/256)

// bf16 helpers: round-to-nearest-even pack, cheap unpack (<<16)
__device__ __forceinline__ unsigned short f2bf(float x) {
  unsigned u = __float_as_uint(x);
  u = (u + 0x7fffu + ((u >> 16) & 1u)) >> 16;
  return (unsigned short)u;
}
#define BFL(u) __uint_as_float((u) << 16)
#define BFH(u) __uint_as_float((u) & 0xffff0000u)

// ---------------- K0: E16 build (packed bf16 pairs, 32B/row) + hist + zero --
__global__ __launch_bounds__(256) void prep_kernel(const float* __restrict__ att,
                                                   unsigned char* __restrict__ E16,
                                                   int* __restrict__ hist,
                                                   float* __restrict__ out) {
  {
    int nthr = gridDim.x * 256;
    int gt = blockIdx.x * 256 + threadIdx.x;
    float4 z4 = make_float4(0.f, 0.f, 0.f, 0.f);
    float4* o4 = (float4*)out;
    for (int i = gt; i < NBAT * CCH * SEQL / 4; i += nthr) o4[i] = z4;
  }
  if (blockIdx.x < ETB) {
    int a = blockIdx.x * 256 + threadIdx.x;
    if (a >= SEQL) return;
    float ad = (float)a;
    float outv[16];
    float log2S = log2f((float)SEQL);
    #pragma unroll
    for (int k = 0; k < 5; ++k) {
      float hl = exp2f(3.0f + (float)k * (log2S - 3.0f) * 0.25f);
      outv[k] = exp2f(-ad / hl);
    }
    const int cw[5] = {1, 3, 7, 15, 31};
    #pragma unroll
    for (int k = 0; k < 5; ++k) outv[5 + k] = (a < cw[k]) ? 1.0f : 0.0f;
    float pmax = 0.0f;
    float pk[5];
    #pragma unroll
    for (int k = 0; k < 5; ++k) {
      float mean = 9000.0f * (float)(k + 1);
      float sd = 4500.0f;
      float cc = (mean / sd) * (mean / sd);      // 4,16,36,64,100
      float rr = mean / (sd * sd);
      float logz = lgammaf(cc) - cc * logf(rr);
      float pp;
      if (a == 0) pp = 1e-8f;                    // xlogy -> -inf -> exp = 0
      else pp = expf((cc - 1.0f) * logf(ad) - rr * ad - logz) + 1e-8f;
      pk[k] = pp;
      float mstar = (cc - 1.0f) / rr;            // 6750..44550, interior mode
      float m0 = floorf(mstar), m1 = m0 + 1.0f;
      if (m1 > (float)(SEQL - 1)) m1 = (float)(SEQL - 1);
      float p0 = expf((cc - 1.0f) * logf(m0) - rr * m0 - logz) + 1e-8f;
      float p1 = expf((cc - 1.0f) * logf(m1) - rr * m1 - logz) + 1e-8f;
      pmax = fmaxf(pmax, fmaxf(p0, p1));
    }
    #pragma unroll
    for (int k = 0; k < 5; ++k) outv[10 + k] = pk[k] / pmax;
    outv[15] = 0.0f;
    unsigned by[16];
    #pragma unroll
    for (int k = 0; k < 15; ++k)
      by[k] = (unsigned)(fminf(fmaxf(outv[k], 0.f), 1.f) * 255.f + 0.5f);
    by[15] = 0u;
    // pack as bf16 pairs (integers 0..255 are exact in bf16)
    unsigned pw[8];
    #pragma unroll
    for (int k = 0; k < 8; ++k)
      pw[k] = (unsigned)f2bf((float)by[2 * k]) |
              ((unsigned)f2bf((float)by[2 * k + 1]) << 16);
    uint4 o0 = make_uint4(pw[0], pw[1], pw[2], pw[3]);
    uint4 o1 = make_uint4(pw[4], pw[5], pw[6], pw[7]);
    uint4* dst = (uint4*)(E16 + (size_t)a * 32);
    dst[0] = o0;
    dst[1] = o1;
  } else {
    int bid = blockIdx.x - ETB;
    int ch4 = bid / TKB;
    int blk = bid % TKB;
    int b = ch4 >> 1, ch = ch4 & 1;
    const float* row = att + ((size_t)b * 3 + 1 + ch) * SEQL;
    int* h = hist + (size_t)ch4 * 65536;
    int per = (SEQL + TKB - 1) / TKB;
    int lo = blk * per;
    int hi = lo + per; if (hi > SEQL) hi = SEQL;
    for (int i = lo + threadIdx.x; i < hi; i += 256)
      atomicAdd(&h[__float_as_uint(row[i]) >> 16], 1);  // vals>=0 -> monotone
  }
}

// ---------------- K1: collect w/ inline threshold (R15 version) -------------
__global__ __launch_bounds__(256) void topk_collect_kernel(
    const float* __restrict__ att, const int* __restrict__ hist,
    unsigned long long* __restrict__ cand, int* __restrict__ cnt) {
  __shared__ int s_scan[256];
  __shared__ int s_aux[2];
  int tid = threadIdx.x;
  int ch4 = blockIdx.x / TKB;
  int blk = blockIdx.x % TKB;
  const int* h = hist + (size_t)ch4 * 65536;
  {
    int base = tid * 256;
    int sum = 0;
    for (int i = 0; i < 64; ++i) {
      int4 v = ((const int4*)(h + base))[i];
      sum += v.x + v.y + v.z + v.w;
    }
    s_scan[tid] = sum;
  }
  __syncthreads();
  for (int d = 1; d < 256; d <<= 1) {
    int v = s_scan[tid] + ((tid + d < 256) ? s_scan[tid + d] : 0);
    __syncthreads();
    s_scan[tid] = v;
    __syncthreads();
  }
  {
    int sufEx = (tid == 255) ? 0 : s_scan[tid + 1];
    if (s_scan[tid] >= 256 && sufEx < 256) { s_aux[0] = tid; s_aux[1] = 256 - sufEx; }
  }
  __syncthreads();
  int chunk = s_aux[0], want = s_aux[1];
  s_scan[tid] = h[chunk * 256 + tid];
  __syncthreads();
  for (int d = 1; d < 256; d <<= 1) {
    int v = s_scan[tid] + ((tid + d < 256) ? s_scan[tid + d] : 0);
    __syncthreads();
    s_scan[tid] = v;
    __syncthreads();
  }
  {
    int sufEx2 = (tid == 255) ? 0 : s_scan[tid + 1];
    if (s_scan[tid] >= want && sufEx2 < want) s_aux[0] = chunk * 256 + tid;
  }
  __syncthreads();
  unsigned T16 = (unsigned)s_aux[0];
  int b = ch4 >> 1, ch = ch4 & 1;
  const float* row = att + ((size_t)b * 3 + 1 + ch) * SEQL;
  int per = (SEQL + TKB - 1) / TKB;
  int lo = blk * per;
  int hi = lo + per; if (hi > SEQL) hi = SEQL;
  for (int i = lo + tid; i < hi; i += 256) {
    unsigned key = __float_as_uint(row[i]);
    if ((key >> 16) >= T16) {
      int p = atomicAdd(&cnt[ch4], 1);
      if (p < CDCAP)
        cand[(size_t)ch4 * CDCAP + p] =
            ((unsigned long long)key << 32) | (unsigned)(~(unsigned)i);
    }
  }
}

// ---------------- K2a: per-channel desc sort -> top-256 (4 parallel blocks) -
__global__ __launch_bounds__(1024) void topk_sort_kernel(
    const unsigned long long* __restrict__ cand, const int* __restrict__ cnt,
    unsigned* __restrict__ chsel) {
  __shared__ unsigned long long sc[CDCAP];
  int ch4 = blockIdx.x, t = threadIdx.x;
  int n = cnt[ch4]; if (n > CDCAP) n = CDCAP;   // >=256 by construction
  int P = 256;
  while (P < n) P <<= 1;                        // typical 512
  for (int i = t; i < P; i += 1024)
    sc[i] = (i < n) ? cand[(size_t)ch4 * CDCAP + i] : 0ull;  // 0 sorts last
  __syncthreads();
  for (int k = 2; k <= P; k <<= 1) {
    for (int j = k >> 1; j > 0; j >>= 1) {
      for (int i = t; i < P; i += 1024) {
        int ixj = i ^ j;
        if (ixj > i) {
          unsigned long long va = sc[i], vb2 = sc[ixj];
          bool up = ((i & k) == 0);
          if ((va < vb2) == up) { sc[i] = vb2; sc[ixj] = va; }
        }
      }
      __syncthreads();
    }
  }
  // desc u64 = value desc, tie -> larger ~i = smaller index first
  if (t < 256)
    chsel[(size_t)ch4 * 256 + t] = ~(unsigned)(sc[t] & 0xFFFFFFFFull);
}

// ---------------- K2b: merge acc+don, ascending sort of 512 -----------------
__global__ __launch_bounds__(512) void topk_merge_kernel(const unsigned* __restrict__ chsel,
                                                         int* __restrict__ idx) {
  __shared__ int m[512];
  int b = blockIdx.x, tid = threadIdx.x;
  m[tid] = (int)chsel[(size_t)b * 512 + tid];
  __syncthreads();
  for (int k = 2; k <= 512; k <<= 1) {
    for (int j = k >> 1; j > 0; j >>= 1) {
      int ixj = tid ^ j;
      if (ixj > tid) {
        int va = m[tid], vb2 = m[ixj];
        bool up = ((tid & k) == 0);
        if ((va > vb2) == up) { m[tid] = vb2; m[ixj] = va; }
      }
      __syncthreads();
    }
  }
  idx[b * 512 + tid] = m[tid];
}

// ---------------- K3: fused gather + LN1 + QKV layer 0 ----------------------
// kbT/vT layout (bf16): [((b*4+h)*4+dpack)*4096 + i*8 + (d&7)]
__global__ __launch_bounds__(128) void gqkv0_kernel(
    const float* __restrict__ x, const int* __restrict__ idx,
    const float* __restrict__ ln_g, const float* __restrict__ ln_b,
    const float* __restrict__ Wq, const float* __restrict__ Wk,
    const float* __restrict__ Wv, const float* __restrict__ Wrel,
    const float* __restrict__ rcb, const float* __restrict__ rpb,
    float* __restrict__ emb, float* __restrict__ qc,
    unsigned short* __restrict__ kbT, unsigned short* __restrict__ vT,
    float* __restrict__ wb) {
  __shared__ float qs[128];
  const int l = 0;
  int hd = threadIdx.x;        // 0..127
  int hh = hd >> 5, d = hd & 31;
  int row = blockIdx.x;        // b*512 + i
  int b = row >> 9, ii = row & 511;
  int li = idx[b * NSEL + ii];
  float h[32];
  float mu = 0.f;
  #pragma unroll
  for (int c = 0; c < 32; ++c) {
    h[c] = x[((size_t)b * CCH + c) * SEQL + li];
    mu += h[c];
  }
  if (hd < 32) emb[(size_t)row * CCH + hd] = h[hd];
  mu *= (1.0f / 32.0f);
  float var = 0.f;
  #pragma unroll
  for (int c = 0; c < 32; ++c) { float dd0 = h[c] - mu; var += dd0 * dd0; }
  var *= (1.0f / 32.0f);
  float rstd = rsqrtf(var + 1e-5f);
  const float* g = ln_g + l * CCH;
  const float* bb = ln_b + l * CCH;
  #pragma unroll
  for (int c = 0; c < 32; ++c) h[c] = (h[c] - mu) * rstd * g[c] + bb[c];
  const float* wq = Wq + (size_t)l * CCH * HDD + hd;
  const float* wk = Wk + (size_t)l * CCH * HDD + hd;
  const float* wv = Wv + (size_t)l * CCH * HDD + hd;
  float q = 0.f, kk = 0.f, vv = 0.f;
  #pragma unroll
  for (int c = 0; c < 32; ++c) {
    q += h[c] * wq[c * HDD];
    kk += h[c] * wk[c * HDD];
    vv += h[c] * wv[c * HDD];
  }
  q *= 0.17677669529663687f;   // DK^-0.5
  qs[hd] = q;
  qc[(size_t)row * HDD + hd] = q + rcb[(l * NHEAD + hh) * DKD + d];
  size_t tpos = ((size_t)(b * 4 + hh) * 4 + (d >> 3)) * 4096 + (size_t)ii * 8 + (d & 7);
  kbT[tpos] = f2bf(kk);
  vT[tpos]  = f2bf(vv);
  __syncthreads();
  if (hd < 120) {
    int h2 = hd / 30, f = hd % 30;
    const float* wr = Wrel + ((size_t)l * 30 + f) * HDD + h2 * DKD;
    const float* rp = rpb + (l * NHEAD + h2) * DKD;
    const float* qsh = qs + h2 * DKD;
    float acc = 0.f;
    #pragma unroll
    for (int dd = 0; dd < 32; ++dd) acc += (qsh[dd] + rp[dd]) * wr[dd];
    wb[((size_t)row * NHEAD + h2) * 32 + f] = acc;   // padded stride 32
  }
}

// ---------------- K4: fused layer, 512 threads = (4 heads x 2 j-halves) -----
// R18: grid 1024 is only 4 blocks/CU -> occupancy was grid-capped at 16
// waves/CU. Split j-dim: 8 waves/block, wave w = (head w>>1, half w&1) does
// 256 of the 512 logits; 2-way online-softmax merge via LDS (smx/ssm);
// partial PV combined in LDS. 4 blocks/CU x 512 thr = 2048 = 100% occupancy.
// MLP: 1 col/thread (512); proj/MLP2: 16 segments.
__global__ __launch_bounds__(512, 8) void layer_kernel(
    const float* __restrict__ qc, const unsigned short* __restrict__ kbT,
    const unsigned short* __restrict__ vT, const float* __restrict__ wbuf,
    const unsigned char* __restrict__ E16, const int* __restrict__ idx,
    const float* __restrict__ Wo, const float* __restrict__ bo,
    const float* __restrict__ ln2_g, const float* __restrict__ ln2_b,
    const float* __restrict__ W1, const float* __restrict__ b1,
    const float* __restrict__ W2, const float* __restrict__ b2,
    const float* __restrict__ ln1_g, const float* __restrict__ ln1_b,
    const float* __restrict__ Wq, const float* __restrict__ Wk,
    const float* __restrict__ Wv, const float* __restrict__ Wrel,
    const float* __restrict__ rcb, const float* __restrict__ rpb,
    float* __restrict__ emb, float* __restrict__ qcN,
    unsigned short* __restrict__ kbTN, unsigned short* __restrict__ vTN,
    float* __restrict__ wbN, float* __restrict__ out, int layer) {
  __shared__ unsigned esb[8 * 512]; // 16KB packed bf16 E pairs; [j*8+7] hi = sign
  __shared__ float obsp[8][32];     // per-wave partial PV
  __shared__ float obs[128];        // combined attn output row
  __shared__ float part[16][32];
  __shared__ float res[32];
  __shared__ float hln[32];
  __shared__ float fin[32];
  __shared__ float a1s[MLPD];
  __shared__ float qs[128];
  __shared__ float smx[8], ssm[8];
  int bid = blockIdx.x;
  int b = bid >> 9;
  int i = bid & 511;
  int tid = threadIdx.x;
  int pos = idx[b * NSEL + i];     // this row's sequence position
  // ---- E-row fetch once per block into LDS (pre-packed bf16) ----
  {
    int j = tid;
    int dj = pos - idx[b * NSEL + j];
    int a = dj < 0 ? -dj : dj;
    const uint4* eg = (const uint4*)(E16 + (size_t)a * 32);
    uint4 e0 = eg[0];
    uint4 e1 = eg[1];
    unsigned sc = dj > 0 ? 0x3F80u : (dj < 0 ? 0xBF80u : 0u);  // bf16(sign)
    e1.w |= (sc << 16);
    uint4* ed = (uint4*)(esb + j * 8);
    ed[0] = e0;
    ed[1] = e1;
  }
  __syncthreads();
  // ---- attention: wave = (head, j-half) ----
  int wv = tid >> 6;               // 0..7
  int h = wv >> 1, hf = wv & 1, ln = tid & 63;
  float lg[4];
  const uint4* kb4 = (const uint4*)kbT + (size_t)(b * 4 + h) * 4 * 512;
  const uint4* vb4 = (const uint4*)vT + (size_t)(b * 4 + h) * 4 * 512;
  {
    const float* qrow = qc + (size_t)(b * NSEL + i) * HDD + h * DKD;
    float q[32];
    #pragma unroll
    for (int d4 = 0; d4 < 8; ++d4) {
      float4 qv = *(const float4*)(qrow + d4 * 4);
      q[d4 * 4 + 0] = qv.x; q[d4 * 4 + 1] = qv.y;
      q[d4 * 4 + 2] = qv.z; q[d4 * 4 + 3] = qv.w;
    }
    const float* wrow = wbuf + ((size_t)(b * NSEL + i) * NHEAD + h) * 32;
    float w0[15], w1[15];
    #pragma unroll
    for (int f = 0; f < 15; ++f) {
      w0[f] = wrow[f] * (1.0f / 255.0f);        // u8 scale folded in
      w1[f] = wrow[15 + f] * (1.0f / 255.0f);
    }
    #pragma unroll
    for (int u = 0; u < 4; ++u) {
      int j = hf * 256 + u * 64 + ln;
      float cacc = 0.f;
      #pragma unroll
      for (int dp = 0; dp < 4; ++dp) {
        uint4 kv = kb4[dp * 512 + j];
        cacc += q[dp * 8 + 0] * BFL(kv.x) + q[dp * 8 + 1] * BFH(kv.x)
              + q[dp * 8 + 2] * BFL(kv.y) + q[dp * 8 + 3] * BFH(kv.y)
              + q[dp * 8 + 4] * BFL(kv.z) + q[dp * 8 + 5] * BFH(kv.z)
              + q[dp * 8 + 6] * BFL(kv.w) + q[dp * 8 + 7] * BFH(kv.w);
      }
      const uint4* ej = (const uint4*)(esb + j * 8);
      uint4 a0 = ej[0];
      uint4 a1 = ej[1];
      float r0, r1;
      r0  = BFL(a0.x) * w0[0]  + BFH(a0.x) * w0[1];
      r1  = BFL(a0.x) * w1[0]  + BFH(a0.x) * w1[1];
      r0 += BFL(a0.y) * w0[2]  + BFH(a0.y) * w0[3];
      r1 += BFL(a0.y) * w1[2]  + BFH(a0.y) * w1[3];
      r0 += BFL(a0.z) * w0[4]  + BFH(a0.z) * w0[5];
      r1 += BFL(a0.z) * w1[4]  + BFH(a0.z) * w1[5];
      r0 += BFL(a0.w) * w0[6]  + BFH(a0.w) * w0[7];
      r1 += BFL(a0.w) * w1[6]  + BFH(a0.w) * w1[7];
      r0 += BFL(a1.x) * w0[8]  + BFH(a1.x) * w0[9];
      r1 += BFL(a1.x) * w1[8]  + BFH(a1.x) * w1[9];
      r0 += BFL(a1.y) * w0[10] + BFH(a1.y) * w0[11];
      r1 += BFL(a1.y) * w1[10] + BFH(a1.y) * w1[11];
      r0 += BFL(a1.z) * w0[12] + BFH(a1.z) * w0[13];
      r1 += BFL(a1.z) * w1[12] + BFH(a1.z) * w1[13];
      r0 += BFL(a1.w) * w0[14];
      r1 += BFL(a1.w) * w1[14];
      lg[u] = cacc + r0 + BFH(a1.w) * r1;
    }
    // partial softmax over this wave's 256 logits
    float m = lg[0];
    #pragma unroll
    for (int u = 1; u < 4; ++u) m = fmaxf(m, lg[u]);
    #pragma unroll
    for (int s = 1; s < 64; s <<= 1) m = fmaxf(m, __shfl_xor(m, s));
    float ssum = 0.f;
    #pragma unroll
    for (int u = 0; u < 4; ++u) { lg[u] = __expf(lg[u] - m); ssum += lg[u]; }
    #pragma unroll
    for (int s = 1; s < 64; s <<= 1) ssum += __shfl_xor(ssum, s);
    if (ln == 0) { smx[wv] = m; ssm[wv] = ssum; }
  }
  __syncthreads();
  // 2-way online-softmax merge
  float factor;
  {
    float m0 = smx[h * 2], m1 = smx[h * 2 + 1];
    float mm = fmaxf(m0, m1);
    float stot = ssm[h * 2] * __expf(m0 - mm) + ssm[h * 2 + 1] * __expf(m1 - mm);
    float mw = hf ? m1 : m0;
    factor = __expf(mw - mm) / stot;
  }
  // partial PV over this wave's 256 keys -> obsp
  #pragma unroll
  for (int dp = 0; dp < 4; ++dp) {
    float acc[8] = {0.f, 0.f, 0.f, 0.f, 0.f, 0.f, 0.f, 0.f};
    #pragma unroll
    for (int u = 0; u < 4; ++u) {
      uint4 vvv = vb4[dp * 512 + hf * 256 + u * 64 + ln];
      float p = lg[u];
      acc[0] += p * BFL(vvv.x); acc[1] += p * BFH(vvv.x);
      acc[2] += p * BFL(vvv.y); acc[3] += p * BFH(vvv.y);
      acc[4] += p * BFL(vvv.z); acc[5] += p * BFH(vvv.z);
      acc[6] += p * BFL(vvv.w); acc[7] += p * BFH(vvv.w);
    }
    #pragma unroll
    for (int s = 1; s < 8; s <<= 1) {
      #pragma unroll
      for (int t = 0; t < 8; ++t) acc[t] += __shfl_xor(acc[t], s);
    }
    int sel = ln & 7;
    float y = acc[0];
    #pragma unroll
    for (int t = 1; t < 8; ++t) y = (sel == t) ? acc[t] : y;
    #pragma unroll
    for (int s = 8; s < 64; s <<= 1) y += __shfl_xor(y, s);
    if (ln < 8) obsp[wv][dp * 8 + ln] = y * factor;
  }
  __syncthreads();
  if (tid < 128)
    obs[tid] = obsp[(tid >> 5) * 2][tid & 31] + obsp[(tid >> 5) * 2 + 1][tid & 31];
  __syncthreads();
  // ---- proj + residual + LN2 + MLP + residual (16 segments) ----
  int c = tid & 31, seg = tid >> 5;
  {
    const float* wo = Wo + (size_t)layer * HDD * CCH + c;
    float pacc = 0.f;
    #pragma unroll
    for (int k = 0; k < 8; ++k) {
      int kk = seg * 8 + k;
      pacc += obs[kk] * wo[kk * CCH];
    }
    part[seg][c] = pacc;
  }
  __syncthreads();
  if (tid < 32) {
    float s = bo[layer * CCH + tid] + emb[(size_t)bid * CCH + tid];
    #pragma unroll
    for (int sg = 0; sg < 16; ++sg) s += part[sg][tid];
    res[tid] = s;
    float mu = 0.f, s2 = 0.f;
    // LN2 needs full res[]; do it after wave-local barrier via shuffle-free
    // path: all 32 lanes are in the same wave, res written by same lanes.
  }
  __syncthreads();
  if (tid < 32) {
    float mu = 0.f, s2 = 0.f;
    #pragma unroll
    for (int c2 = 0; c2 < 32; ++c2) { float v = res[c2]; mu += v; s2 += v * v; }
    mu *= (1.0f / 32.0f);
    float var = s2 * (1.0f / 32.0f) - mu * mu;
    float rstd = rsqrtf(var + 1e-5f);
    hln[tid] = (res[tid] - mu) * rstd * ln2_g[layer * CCH + tid] + ln2_b[layer * CCH + tid];
  }
  __syncthreads();
  {
    const float* w1 = W1 + (size_t)layer * CCH * MLPD;
    float accA = b1[layer * MLPD + tid];
    for (int c2 = 0; c2 < 32; ++c2) accA += hln[c2] * w1[c2 * MLPD + tid];
    a1s[tid] = 0.5f * accA * (1.0f + erff(accA * 0.70710678118654752f));
  }
  __syncthreads();
  {
    const float* w2 = W2 + (size_t)layer * MLPD * CCH;
    float acc2 = 0.f;
    #pragma unroll 4
    for (int mi = 0; mi < 32; ++mi) {
      int m = seg * 32 + mi;
      acc2 += a1s[m] * w2[m * CCH + c];
    }
    __syncthreads();                    // part[] reuse
    part[seg][c] = acc2;
  }
  __syncthreads();
  if (tid < 32) {
    float s = b2[layer * CCH + tid] + res[tid];
    #pragma unroll
    for (int sg = 0; sg < 16; ++sg) s += part[sg][tid];
    fin[tid] = s;
    if (layer < 3) emb[(size_t)bid * CCH + tid] = s;
  }
  __syncthreads();
  if (layer == 3) {
    if (tid < 32) out[((size_t)b * CCH + tid) * SEQL + pos] = fin[tid];
    return;
  }
  // ---- qkv for layer l+1 (into the ping-pong "next" buffers) ----
  const int l1 = layer + 1;
  bool act = tid < 128;
  int hd = tid & 127;
  int hh2 = hd >> 5, dd2 = hd & 31;
  if (act) {
    float hx[32];
    float mu = 0.f;
    #pragma unroll
    for (int c2 = 0; c2 < 32; ++c2) { hx[c2] = fin[c2]; mu += hx[c2]; }
    mu *= (1.0f / 32.0f);
    float var = 0.f;
    #pragma unroll
    for (int c2 = 0; c2 < 32; ++c2) { float dd = hx[c2] - mu; var += dd * dd; }
    var *= (1.0f / 32.0f);
    float rstd = rsqrtf(var + 1e-5f);
    const float* g = ln1_g + l1 * CCH;
    const float* bb = ln1_b + l1 * CCH;
    #pragma unroll
    for (int c2 = 0; c2 < 32; ++c2) hx[c2] = (hx[c2] - mu) * rstd * g[c2] + bb[c2];
    const float* wq = Wq + (size_t)l1 * CCH * HDD + hd;
    const float* wk = Wk + (size_t)l1 * CCH * HDD + hd;
    const float* wv = Wv + (size_t)l1 * CCH * HDD + hd;
    float q = 0.f, kk = 0.f, vvv = 0.f;
    #pragma unroll
    for (int c2 = 0; c2 < 32; ++c2) {
      q += hx[c2] * wq[c2 * HDD];
      kk += hx[c2] * wk[c2 * HDD];
      vvv += hx[c2] * wv[c2 * HDD];
    }
    q *= 0.17677669529663687f;
    qs[hd] = q;
    qcN[(size_t)bid * HDD + hd] = q + rcb[(l1 * NHEAD + hh2) * DKD + dd2];
    size_t tpos = ((size_t)(b * 4 + hh2) * 4 + (dd2 >> 3)) * 4096 + (size_t)i * 8 + (dd2 & 7);
    kbTN[tpos] = f2bf(kk);
    vTN[tpos]  = f2bf(vvv);
  }
  __syncthreads();
  if (act && hd < 120) {
    int h2 = hd / 30, f = hd % 30;
    const float* rp = rpb + (l1 * NHEAD + h2) * DKD;
    const float* wr = Wrel + ((size_t)l1 * 30 + f) * HDD + h2 * DKD;
    const float* qsh = qs + h2 * DKD;
    float acc = 0.f;
    #pragma unroll
    for (int dd = 0; dd < 32; ++dd) acc += (qsh[dd] + rp[dd]) * wr[dd];
    wbN[((size_t)bid * NHEAD + h2) * 32 + f] = acc;
  }
}

extern "C" void kernel_launch(void* const* d_in, const int* in_sizes, int n_in,
                              void* d_out, int out_size, void* d_ws, size_t ws_size,
                              hipStream_t stream) {
  (void)in_sizes; (void)n_in; (void)ws_size; (void)out_size;
  const float* x_skip    = (const float*)d_in[0];
  const float* attention = (const float*)d_in[1];
  const float* ln1_g = (const float*)d_in[2];
  const float* ln1_b = (const float*)d_in[3];
  const float* Wq    = (const float*)d_in[4];
  const float* Wk    = (const float*)d_in[5];
  const float* Wv    = (const float*)d_in[6];
  const float* Wrel  = (const float*)d_in[7];
  const float* rcb   = (const float*)d_in[8];
  const float* rpb   = (const float*)d_in[9];
  const float* Wo    = (const float*)d_in[10];
  const float* bo    = (const float*)d_in[11];
  const float* ln2_g = (const float*)d_in[12];
  const float* ln2_b = (const float*)d_in[13];
  const float* W1    = (const float*)d_in[14];
  const float* b1    = (const float*)d_in[15];
  const float* W2    = (const float*)d_in[16];
  const float* b2    = (const float*)d_in[17];
  float* out = (float*)d_out;
  char* ws = (char*)d_ws;

  unsigned char* E16 = (unsigned char*)(ws + 0);      // 45000*32 = 1,440,000
  int*      idx   = (int*)(ws + 1441792);             // 4,096
  float*    emb   = (float*)(ws + 1445888);           // 131,072
  float*    qcA   = (float*)(ws + 1576960);           // 524,288
  unsigned short* kbTA = (unsigned short*)(ws + 2101248); // 262,144
  unsigned short* vTA  = (unsigned short*)(ws + 2363392); // 262,144
  float*    wbA   = (float*)(ws + 2625536);           // 524,288
  unsigned short* kbTB = (unsigned short*)(ws + 3149824); // 262,144
  unsigned short* vTB  = (unsigned short*)(ws + 3411968); // 262,144
  int*      hist  = (int*)(ws + 3674112);             // 1,048,576
  int*      cnt   = (int*)(ws + 4722688);             // 16
  unsigned long long* cand = (unsigned long long*)(ws + 4722720); // 65,536
  unsigned* chsel = (unsigned*)(ws + 4788256);        // 4,096 -> ends 4,792,352
  float*    qcB   = (float*)(ws + 4792352);           // 524,288
  float*    wbB   = (float*)(ws + 5316640);           // 524,288 -> ends 5,840,928

  hipMemsetAsync(ws + 3674112, 0, 1048576 + 32, stream);   // hist + cnt
  prep_kernel<<<ETB + 4 * TKB, 256, 0, stream>>>(attention, E16, hist, out);
  topk_collect_kernel<<<4 * TKB, 256, 0, stream>>>(attention, hist, cand, cnt);
  topk_sort_kernel<<<4, 1024, 0, stream>>>(cand, cnt, chsel);
  topk_merge_kernel<<<2, 512, 0, stream>>>(chsel, idx);
  gqkv0_kernel<<<1024, 128, 0, stream>>>(x_skip, idx, ln1_g, ln1_b, Wq, Wk, Wv,
                                         Wrel, rcb, rpb, emb, qcA, kbTA, vTA, wbA);
  for (int l = 0; l < 4; ++l) {
    const float* qcI = (l & 1) ? qcB : qcA;
    const unsigned short* kbI = (l & 1) ? kbTB : kbTA;
    const unsigned short* vI  = (l & 1) ? vTB : vTA;
    const float* wbI = (l & 1) ? wbB : wbA;
    float* qcO = (l & 1) ? qcA : qcB;
    unsigned short* kbO = (l & 1) ? kbTA : kbTB;
    unsigned short* vO  = (l & 1) ? vTA : vTB;
    float* wbO = (l & 1) ? wbA : wbB;
    layer_kernel<<<1024, 512, 0, stream>>>(qcI, kbI, vI, wbI, E16, idx,
                                           Wo, bo, ln2_g, ln2_b, W1, b1, W2, b2,
                                           ln1_g, ln1_b, Wq, Wk, Wv, Wrel, rcb,
                                           rpb, emb, qcO, kbO, vO, wbO, out, l);
  }
}

// Round 7
// 318.019 us; speedup vs baseline: 1.6674x; 1.6674x over previous
//
#include <hip/hip_runtime.h>
#include <math.h>

#define SEQL   45000
#define NBAT   2
#define CCH    32
#define NSEL   512
#define NHEAD  4
#define DKD    32
#define HDD    128
#define MLPD   512
#define CDCAP  2048
#define TKB    32     // scan slices per (b,channel)
#define ETB    176    // etab blocks = ceil(45000/256)

// bf16 helpers: round-to-nearest-even pack, cheap unpack (<<16)
__device__ __forceinline__ unsigned short f2bf(float x) {
  unsigned u = __float_as_uint(x);
  u = (u + 0x7fffu + ((u >> 16) & 1u)) >> 16;
  return (unsigned short)u;
}
#define BFL(u) __uint_as_float((u) << 16)
#define BFH(u) __uint_as_float((u) & 0xffff0000u)

// ---------------- K0: E16 build (packed bf16 pairs, 32B/row) + hist + zero --
__global__ __launch_bounds__(256) void prep_kernel(const float* __restrict__ att,
                                                   unsigned char* __restrict__ E16,
                                                   int* __restrict__ hist,
                                                   float* __restrict__ out) {
  {
    int nthr = gridDim.x * 256;
    int gt = blockIdx.x * 256 + threadIdx.x;
    float4 z4 = make_float4(0.f, 0.f, 0.f, 0.f);
    float4* o4 = (float4*)out;
    for (int i = gt; i < NBAT * CCH * SEQL / 4; i += nthr) o4[i] = z4;
  }
  if (blockIdx.x < ETB) {
    int a = blockIdx.x * 256 + threadIdx.x;
    if (a >= SEQL) return;
    float ad = (float)a;
    float outv[16];
    float log2S = log2f((float)SEQL);
    #pragma unroll
    for (int k = 0; k < 5; ++k) {
      float hl = exp2f(3.0f + (float)k * (log2S - 3.0f) * 0.25f);
      outv[k] = exp2f(-ad / hl);
    }
    const int cw[5] = {1, 3, 7, 15, 31};
    #pragma unroll
    for (int k = 0; k < 5; ++k) outv[5 + k] = (a < cw[k]) ? 1.0f : 0.0f;
    float pmax = 0.0f;
    float pk[5];
    #pragma unroll
    for (int k = 0; k < 5; ++k) {
      float mean = 9000.0f * (float)(k + 1);
      float sd = 4500.0f;
      float cc = (mean / sd) * (mean / sd);      // 4,16,36,64,100
      float rr = mean / (sd * sd);
      float logz = lgammaf(cc) - cc * logf(rr);
      float pp;
      if (a == 0) pp = 1e-8f;                    // xlogy -> -inf -> exp = 0
      else pp = expf((cc - 1.0f) * logf(ad) - rr * ad - logz) + 1e-8f;
      pk[k] = pp;
      float mstar = (cc - 1.0f) / rr;            // 6750..44550, interior mode
      float m0 = floorf(mstar), m1 = m0 + 1.0f;
      if (m1 > (float)(SEQL - 1)) m1 = (float)(SEQL - 1);
      float p0 = expf((cc - 1.0f) * logf(m0) - rr * m0 - logz) + 1e-8f;
      float p1 = expf((cc - 1.0f) * logf(m1) - rr * m1 - logz) + 1e-8f;
      pmax = fmaxf(pmax, fmaxf(p0, p1));
    }
    #pragma unroll
    for (int k = 0; k < 5; ++k) outv[10 + k] = pk[k] / pmax;
    outv[15] = 0.0f;
    unsigned by[16];
    #pragma unroll
    for (int k = 0; k < 15; ++k)
      by[k] = (unsigned)(fminf(fmaxf(outv[k], 0.f), 1.f) * 255.f + 0.5f);
    by[15] = 0u;
    // pack as bf16 pairs (integers 0..255 are exact in bf16)
    unsigned pw[8];
    #pragma unroll
    for (int k = 0; k < 8; ++k)
      pw[k] = (unsigned)f2bf((float)by[2 * k]) |
              ((unsigned)f2bf((float)by[2 * k + 1]) << 16);
    uint4 o0 = make_uint4(pw[0], pw[1], pw[2], pw[3]);
    uint4 o1 = make_uint4(pw[4], pw[5], pw[6], pw[7]);
    uint4* dst = (uint4*)(E16 + (size_t)a * 32);
    dst[0] = o0;
    dst[1] = o1;
  } else {
    int bid = blockIdx.x - ETB;
    int ch4 = bid / TKB;
    int blk = bid % TKB;
    int b = ch4 >> 1, ch = ch4 & 1;
    const float* row = att + ((size_t)b * 3 + 1 + ch) * SEQL;
    int* h = hist + (size_t)ch4 * 65536;
    int per = (SEQL + TKB - 1) / TKB;
    int lo = blk * per;
    int hi = lo + per; if (hi > SEQL) hi = SEQL;
    for (int i = lo + threadIdx.x; i < hi; i += 256)
      atomicAdd(&h[__float_as_uint(row[i]) >> 16], 1);  // vals>=0 -> monotone
  }
}

// ---------------- K1: collect w/ inline threshold (R15 version) -------------
__global__ __launch_bounds__(256) void topk_collect_kernel(
    const float* __restrict__ att, const int* __restrict__ hist,
    unsigned long long* __restrict__ cand, int* __restrict__ cnt) {
  __shared__ int s_scan[256];
  __shared__ int s_aux[2];
  int tid = threadIdx.x;
  int ch4 = blockIdx.x / TKB;
  int blk = blockIdx.x % TKB;
  const int* h = hist + (size_t)ch4 * 65536;
  {
    int base = tid * 256;
    int sum = 0;
    for (int i = 0; i < 64; ++i) {
      int4 v = ((const int4*)(h + base))[i];
      sum += v.x + v.y + v.z + v.w;
    }
    s_scan[tid] = sum;
  }
  __syncthreads();
  for (int d = 1; d < 256; d <<= 1) {
    int v = s_scan[tid] + ((tid + d < 256) ? s_scan[tid + d] : 0);
    __syncthreads();
    s_scan[tid] = v;
    __syncthreads();
  }
  {
    int sufEx = (tid == 255) ? 0 : s_scan[tid + 1];
    if (s_scan[tid] >= 256 && sufEx < 256) { s_aux[0] = tid; s_aux[1] = 256 - sufEx; }
  }
  __syncthreads();
  int chunk = s_aux[0], want = s_aux[1];
  s_scan[tid] = h[chunk * 256 + tid];
  __syncthreads();
  for (int d = 1; d < 256; d <<= 1) {
    int v = s_scan[tid] + ((tid + d < 256) ? s_scan[tid + d] : 0);
    __syncthreads();
    s_scan[tid] = v;
    __syncthreads();
  }
  {
    int sufEx2 = (tid == 255) ? 0 : s_scan[tid + 1];
    if (s_scan[tid] >= want && sufEx2 < want) s_aux[0] = chunk * 256 + tid;
  }
  __syncthreads();
  unsigned T16 = (unsigned)s_aux[0];
  int b = ch4 >> 1, ch = ch4 & 1;
  const float* row = att + ((size_t)b * 3 + 1 + ch) * SEQL;
  int per = (SEQL + TKB - 1) / TKB;
  int lo = blk * per;
  int hi = lo + per; if (hi > SEQL) hi = SEQL;
  for (int i = lo + tid; i < hi; i += 256) {
    unsigned key = __float_as_uint(row[i]);
    if ((key >> 16) >= T16) {
      int p = atomicAdd(&cnt[ch4], 1);
      if (p < CDCAP)
        cand[(size_t)ch4 * CDCAP + p] =
            ((unsigned long long)key << 32) | (unsigned)(~(unsigned)i);
    }
  }
}

// ---------------- K2a: per-channel desc sort -> top-256 (4 parallel blocks) -
__global__ __launch_bounds__(1024) void topk_sort_kernel(
    const unsigned long long* __restrict__ cand, const int* __restrict__ cnt,
    unsigned* __restrict__ chsel) {
  __shared__ unsigned long long sc[CDCAP];
  int ch4 = blockIdx.x, t = threadIdx.x;
  int n = cnt[ch4]; if (n > CDCAP) n = CDCAP;   // >=256 by construction
  int P = 256;
  while (P < n) P <<= 1;                        // typical 512
  for (int i = t; i < P; i += 1024)
    sc[i] = (i < n) ? cand[(size_t)ch4 * CDCAP + i] : 0ull;  // 0 sorts last
  __syncthreads();
  for (int k = 2; k <= P; k <<= 1) {
    for (int j = k >> 1; j > 0; j >>= 1) {
      for (int i = t; i < P; i += 1024) {
        int ixj = i ^ j;
        if (ixj > i) {
          unsigned long long va = sc[i], vb2 = sc[ixj];
          bool up = ((i & k) == 0);
          if ((va < vb2) == up) { sc[i] = vb2; sc[ixj] = va; }
        }
      }
      __syncthreads();
    }
  }
  // desc u64 = value desc, tie -> larger ~i = smaller index first
  if (t < 256)
    chsel[(size_t)ch4 * 256 + t] = ~(unsigned)(sc[t] & 0xFFFFFFFFull);
}

// ---------------- K2b: merge acc+don, ascending sort of 512 -----------------
__global__ __launch_bounds__(512) void topk_merge_kernel(const unsigned* __restrict__ chsel,
                                                         int* __restrict__ idx) {
  __shared__ int m[512];
  int b = blockIdx.x, tid = threadIdx.x;
  m[tid] = (int)chsel[(size_t)b * 512 + tid];
  __syncthreads();
  for (int k = 2; k <= 512; k <<= 1) {
    for (int j = k >> 1; j > 0; j >>= 1) {
      int ixj = tid ^ j;
      if (ixj > tid) {
        int va = m[tid], vb2 = m[ixj];
        bool up = ((tid & k) == 0);
        if ((va > vb2) == up) { m[tid] = vb2; m[ixj] = va; }
      }
      __syncthreads();
    }
  }
  idx[b * 512 + tid] = m[tid];
}

// ---------------- K3: fused gather + LN1 + QKV layer 0 ----------------------
// kbT/vT layout (bf16): [((b*4+h)*4+dpack)*4096 + i*8 + (d&7)]
__global__ __launch_bounds__(128) void gqkv0_kernel(
    const float* __restrict__ x, const int* __restrict__ idx,
    const float* __restrict__ ln_g, const float* __restrict__ ln_b,
    const float* __restrict__ Wq, const float* __restrict__ Wk,
    const float* __restrict__ Wv, const float* __restrict__ Wrel,
    const float* __restrict__ rcb, const float* __restrict__ rpb,
    float* __restrict__ emb, float* __restrict__ qc,
    unsigned short* __restrict__ kbT, unsigned short* __restrict__ vT,
    float* __restrict__ wb) {
  __shared__ float qs[128];
  const int l = 0;
  int hd = threadIdx.x;        // 0..127
  int hh = hd >> 5, d = hd & 31;
  int row = blockIdx.x;        // b*512 + i
  int b = row >> 9, ii = row & 511;
  int li = idx[b * NSEL + ii];
  float h[32];
  float mu = 0.f;
  #pragma unroll
  for (int c = 0; c < 32; ++c) {
    h[c] = x[((size_t)b * CCH + c) * SEQL + li];
    mu += h[c];
  }
  if (hd < 32) emb[(size_t)row * CCH + hd] = h[hd];
  mu *= (1.0f / 32.0f);
  float var = 0.f;
  #pragma unroll
  for (int c = 0; c < 32; ++c) { float dd0 = h[c] - mu; var += dd0 * dd0; }
  var *= (1.0f / 32.0f);
  float rstd = rsqrtf(var + 1e-5f);
  const float* g = ln_g + l * CCH;
  const float* bb = ln_b + l * CCH;
  #pragma unroll
  for (int c = 0; c < 32; ++c) h[c] = (h[c] - mu) * rstd * g[c] + bb[c];
  const float* wq = Wq + (size_t)l * CCH * HDD + hd;
  const float* wk = Wk + (size_t)l * CCH * HDD + hd;
  const float* wv = Wv + (size_t)l * CCH * HDD + hd;
  float q = 0.f, kk = 0.f, vv = 0.f;
  #pragma unroll
  for (int c = 0; c < 32; ++c) {
    q += h[c] * wq[c * HDD];
    kk += h[c] * wk[c * HDD];
    vv += h[c] * wv[c * HDD];
  }
  q *= 0.17677669529663687f;   // DK^-0.5
  qs[hd] = q;
  qc[(size_t)row * HDD + hd] = q + rcb[(l * NHEAD + hh) * DKD + d];
  size_t tpos = ((size_t)(b * 4 + hh) * 4 + (d >> 3)) * 4096 + (size_t)ii * 8 + (d & 7);
  kbT[tpos] = f2bf(kk);
  vT[tpos]  = f2bf(vv);
  __syncthreads();
  if (hd < 120) {
    int h2 = hd / 30, f = hd % 30;
    const float* wr = Wrel + ((size_t)l * 30 + f) * HDD + h2 * DKD;
    const float* rp = rpb + (l * NHEAD + h2) * DKD;
    const float* qsh = qs + h2 * DKD;
    float acc = 0.f;
    #pragma unroll
    for (int dd = 0; dd < 32; ++dd) acc += (qsh[dd] + rp[dd]) * wr[dd];
    wb[((size_t)row * NHEAD + h2) * 32 + f] = acc;   // padded stride 32
  }
}

// ---------------- K4: fused layer = attn + proj/LN2/MLP + qkv(l+1) ----------
// R19: revert to R17 structure (256 thr, (256,4), 64 VGPR, no spill — R18's
// 512-thr/(512,8) variant spilled: VGPR capped 64 < ~80 live state -> 146MB
// scratch fetch/dispatch). One fix kept: es LDS layout is PLANE-MAJOR
// esp[p*512+j] so lane j reads stride-1 (conflict-free; R17's esb[j*8] uint4
// was a 16-way bank conflict, 655K conflict-cycles/dispatch in R18's PMC).
__global__ __launch_bounds__(256, 4) void layer_kernel(
    const float* __restrict__ qc, const unsigned short* __restrict__ kbT,
    const unsigned short* __restrict__ vT, const float* __restrict__ wbuf,
    const unsigned char* __restrict__ E16, const int* __restrict__ idx,
    const float* __restrict__ Wo, const float* __restrict__ bo,
    const float* __restrict__ ln2_g, const float* __restrict__ ln2_b,
    const float* __restrict__ W1, const float* __restrict__ b1,
    const float* __restrict__ W2, const float* __restrict__ b2,
    const float* __restrict__ ln1_g, const float* __restrict__ ln1_b,
    const float* __restrict__ Wq, const float* __restrict__ Wk,
    const float* __restrict__ Wv, const float* __restrict__ Wrel,
    const float* __restrict__ rcb, const float* __restrict__ rpb,
    float* __restrict__ emb, float* __restrict__ qcN,
    unsigned short* __restrict__ kbTN, unsigned short* __restrict__ vTN,
    float* __restrict__ wbN, float* __restrict__ out, int layer) {
  __shared__ unsigned esp[8 * 512]; // 16KB plane-major: esp[p*512+j] = bf16 pair (feat 2p,2p+1); p=7 hi = sign
  __shared__ float obs[128];        // attn output row (LDS-resident)
  __shared__ float part[8][32];
  __shared__ float res[32];
  __shared__ float hln[32];
  __shared__ float fin[32];
  __shared__ float a1s[MLPD];
  __shared__ float qs[128];
  int bid = blockIdx.x;
  int b = bid >> 9;
  int i = bid & 511;
  int tid = threadIdx.x;
  int pos = idx[b * NSEL + i];     // this row's sequence position
  // ---- E-row fetch once per block into LDS (pre-packed bf16, plane-major) --
  #pragma unroll
  for (int rep = 0; rep < 2; ++rep) {
    int j = tid + rep * 256;
    int dj = pos - idx[b * NSEL + j];
    int a = dj < 0 ? -dj : dj;
    const uint4* eg = (const uint4*)(E16 + (size_t)a * 32);
    uint4 e0 = eg[0];
    uint4 e1 = eg[1];
    unsigned sc = dj > 0 ? 0x3F80u : (dj < 0 ? 0xBF80u : 0u);  // bf16(sign)
    e1.w |= (sc << 16);
    esp[0 * 512 + j] = e0.x;
    esp[1 * 512 + j] = e0.y;
    esp[2 * 512 + j] = e0.z;
    esp[3 * 512 + j] = e0.w;
    esp[4 * 512 + j] = e1.x;
    esp[5 * 512 + j] = e1.y;
    esp[6 * 512 + j] = e1.z;
    esp[7 * 512 + j] = e1.w;
  }
  __syncthreads();
  // ---- attention: wave = head ----
  {
    int h = tid >> 6, ln = tid & 63;
    const float* qrow = qc + (size_t)(b * NSEL + i) * HDD + h * DKD;
    float q[32];
    #pragma unroll
    for (int d4 = 0; d4 < 8; ++d4) {
      float4 qv = *(const float4*)(qrow + d4 * 4);
      q[d4 * 4 + 0] = qv.x; q[d4 * 4 + 1] = qv.y;
      q[d4 * 4 + 2] = qv.z; q[d4 * 4 + 3] = qv.w;
    }
    const float* wrow = wbuf + ((size_t)(b * NSEL + i) * NHEAD + h) * 32;
    float w0[15], w1[15];
    #pragma unroll
    for (int f = 0; f < 15; ++f) {
      w0[f] = wrow[f] * (1.0f / 255.0f);        // u8 scale folded in
      w1[f] = wrow[15 + f] * (1.0f / 255.0f);
    }
    const uint4* kb4 = (const uint4*)kbT + (size_t)(b * 4 + h) * 4 * 512;
    const uint4* vb4 = (const uint4*)vT + (size_t)(b * 4 + h) * 4 * 512;
    float lg[8];
    #pragma unroll
    for (int u = 0; u < 8; ++u) {
      int j = u * 64 + ln;
      float cacc = 0.f;
      #pragma unroll
      for (int dp = 0; dp < 4; ++dp) {
        uint4 kv = kb4[dp * 512 + j];
        cacc += q[dp * 8 + 0] * BFL(kv.x) + q[dp * 8 + 1] * BFH(kv.x)
              + q[dp * 8 + 2] * BFL(kv.y) + q[dp * 8 + 3] * BFH(kv.y)
              + q[dp * 8 + 4] * BFL(kv.z) + q[dp * 8 + 5] * BFH(kv.z)
              + q[dp * 8 + 6] * BFL(kv.w) + q[dp * 8 + 7] * BFH(kv.w);
      }
      unsigned a0 = esp[0 * 512 + j];
      unsigned a1 = esp[1 * 512 + j];
      unsigned a2 = esp[2 * 512 + j];
      unsigned a3 = esp[3 * 512 + j];
      unsigned a4 = esp[4 * 512 + j];
      unsigned a5 = esp[5 * 512 + j];
      unsigned a6 = esp[6 * 512 + j];
      unsigned a7 = esp[7 * 512 + j];
      float r0, r1;
      r0  = BFL(a0) * w0[0]  + BFH(a0) * w0[1];
      r1  = BFL(a0) * w1[0]  + BFH(a0) * w1[1];
      r0 += BFL(a1) * w0[2]  + BFH(a1) * w0[3];
      r1 += BFL(a1) * w1[2]  + BFH(a1) * w1[3];
      r0 += BFL(a2) * w0[4]  + BFH(a2) * w0[5];
      r1 += BFL(a2) * w1[4]  + BFH(a2) * w1[5];
      r0 += BFL(a3) * w0[6]  + BFH(a3) * w0[7];
      r1 += BFL(a3) * w1[6]  + BFH(a3) * w1[7];
      r0 += BFL(a4) * w0[8]  + BFH(a4) * w0[9];
      r1 += BFL(a4) * w1[8]  + BFH(a4) * w1[9];
      r0 += BFL(a5) * w0[10] + BFH(a5) * w0[11];
      r1 += BFL(a5) * w1[10] + BFH(a5) * w1[11];
      r0 += BFL(a6) * w0[12] + BFH(a6) * w0[13];
      r1 += BFL(a6) * w1[12] + BFH(a6) * w1[13];
      r0 += BFL(a7) * w0[14];
      r1 += BFL(a7) * w1[14];
      lg[u] = cacc + r0 + BFH(a7) * r1;
    }
    // full-row softmax across the wave (512 logits, 8/lane), in registers
    float m = lg[0];
    #pragma unroll
    for (int u = 1; u < 8; ++u) m = fmaxf(m, lg[u]);
    #pragma unroll
    for (int s = 1; s < 64; s <<= 1) m = fmaxf(m, __shfl_xor(m, s));
    float ssum = 0.f;
    #pragma unroll
    for (int u = 0; u < 8; ++u) { lg[u] = __expf(lg[u] - m); ssum += lg[u]; }
    #pragma unroll
    for (int s = 1; s < 64; s <<= 1) ssum += __shfl_xor(ssum, s);
    float invs = 1.0f / ssum;
    // PV: p in registers, v coalesced; reduced-shuffle epilogue -> LDS obs
    #pragma unroll
    for (int dp = 0; dp < 4; ++dp) {
      float acc[8] = {0.f, 0.f, 0.f, 0.f, 0.f, 0.f, 0.f, 0.f};
      #pragma unroll
      for (int u = 0; u < 8; ++u) {
        uint4 vv = vb4[dp * 512 + u * 64 + ln];
        float p = lg[u];
        acc[0] += p * BFL(vv.x); acc[1] += p * BFH(vv.x);
        acc[2] += p * BFL(vv.y); acc[3] += p * BFH(vv.y);
        acc[4] += p * BFL(vv.z); acc[5] += p * BFH(vv.z);
        acc[6] += p * BFL(vv.w); acc[7] += p * BFH(vv.w);
      }
      #pragma unroll
      for (int s = 1; s < 8; s <<= 1) {
        #pragma unroll
        for (int t = 0; t < 8; ++t) acc[t] += __shfl_xor(acc[t], s);
      }
      int sel = ln & 7;
      float y = acc[0];
      #pragma unroll
      for (int t = 1; t < 8; ++t) y = (sel == t) ? acc[t] : y;
      #pragma unroll
      for (int s = 8; s < 64; s <<= 1) y += __shfl_xor(y, s);
      if (ln < 8) obs[h * DKD + dp * 8 + ln] = y * invs;
    }
  }
  __syncthreads();
  // ---- proj + residual + LN2 + MLP + residual ----
  int c = tid & 31, seg = tid >> 5;
  {
    const float* wo = Wo + (size_t)layer * HDD * CCH + c;
    float pacc = 0.f;
    #pragma unroll
    for (int k = 0; k < 16; ++k) {
      int kk = seg * 16 + k;
      pacc += obs[kk] * wo[kk * CCH];
    }
    part[seg][c] = pacc;
  }
  __syncthreads();
  if (tid < 32) {
    float s = bo[layer * CCH + tid] + emb[(size_t)bid * CCH + tid];
    #pragma unroll
    for (int sg = 0; sg < 8; ++sg) s += part[sg][tid];
    res[tid] = s;
  }
  __syncthreads();
  if (tid < 32) {
    float mu = 0.f, s2 = 0.f;
    #pragma unroll
    for (int c2 = 0; c2 < 32; ++c2) { float v = res[c2]; mu += v; s2 += v * v; }
    mu *= (1.0f / 32.0f);
    float var = s2 * (1.0f / 32.0f) - mu * mu;
    float rstd = rsqrtf(var + 1e-5f);
    hln[tid] = (res[tid] - mu) * rstd * ln2_g[layer * CCH + tid] + ln2_b[layer * CCH + tid];
  }
  __syncthreads();
  {
    const float* w1 = W1 + (size_t)layer * CCH * MLPD;
    float accA = b1[layer * MLPD + tid];
    float accB = b1[layer * MLPD + tid + 256];
    for (int c2 = 0; c2 < 32; ++c2) {
      float hv = hln[c2];
      accA += hv * w1[c2 * MLPD + tid];
      accB += hv * w1[c2 * MLPD + tid + 256];
    }
    a1s[tid]       = 0.5f * accA * (1.0f + erff(accA * 0.70710678118654752f));
    a1s[tid + 256] = 0.5f * accB * (1.0f + erff(accB * 0.70710678118654752f));
  }
  __syncthreads();
  {
    const float* w2 = W2 + (size_t)layer * MLPD * CCH;
    float acc2 = 0.f;
    #pragma unroll 4
    for (int mi = 0; mi < 64; ++mi) {
      int m = seg * 64 + mi;
      acc2 += a1s[m] * w2[m * CCH + c];
    }
    __syncthreads();                    // part[] reuse
    part[seg][c] = acc2;
  }
  __syncthreads();
  if (tid < 32) {
    float s = b2[layer * CCH + tid] + res[tid];
    #pragma unroll
    for (int sg = 0; sg < 8; ++sg) s += part[sg][tid];
    fin[tid] = s;
    if (layer < 3) emb[(size_t)bid * CCH + tid] = s;
  }
  __syncthreads();
  if (layer == 3) {
    if (tid < 32) out[((size_t)b * CCH + tid) * SEQL + pos] = fin[tid];
    return;
  }
  // ---- qkv for layer l+1 (into the ping-pong "next" buffers) ----
  const int l1 = layer + 1;
  bool act = tid < 128;
  int hd = tid & 127;
  int hh2 = hd >> 5, dd2 = hd & 31;
  if (act) {
    float hx[32];
    float mu = 0.f;
    #pragma unroll
    for (int c2 = 0; c2 < 32; ++c2) { hx[c2] = fin[c2]; mu += hx[c2]; }
    mu *= (1.0f / 32.0f);
    float var = 0.f;
    #pragma unroll
    for (int c2 = 0; c2 < 32; ++c2) { float dd = hx[c2] - mu; var += dd * dd; }
    var *= (1.0f / 32.0f);
    float rstd = rsqrtf(var + 1e-5f);
    const float* g = ln1_g + l1 * CCH;
    const float* bb = ln1_b + l1 * CCH;
    #pragma unroll
    for (int c2 = 0; c2 < 32; ++c2) hx[c2] = (hx[c2] - mu) * rstd * g[c2] + bb[c2];
    const float* wq = Wq + (size_t)l1 * CCH * HDD + hd;
    const float* wk = Wk + (size_t)l1 * CCH * HDD + hd;
    const float* wv = Wv + (size_t)l1 * CCH * HDD + hd;
    float q = 0.f, kk = 0.f, vv = 0.f;
    #pragma unroll
    for (int c2 = 0; c2 < 32; ++c2) {
      q += hx[c2] * wq[c2 * HDD];
      kk += hx[c2] * wk[c2 * HDD];
      vv += hx[c2] * wv[c2 * HDD];
    }
    q *= 0.17677669529663687f;
    qs[hd] = q;
    qcN[(size_t)bid * HDD + hd] = q + rcb[(l1 * NHEAD + hh2) * DKD + dd2];
    size_t tpos = ((size_t)(b * 4 + hh2) * 4 + (dd2 >> 3)) * 4096 + (size_t)i * 8 + (dd2 & 7);
    kbTN[tpos] = f2bf(kk);
    vTN[tpos]  = f2bf(vv);
  }
  __syncthreads();
  if (act && hd < 120) {
    int h2 = hd / 30, f = hd % 30;
    const float* rp = rpb + (l1 * NHEAD + h2) * DKD;
    const float* wr = Wrel + ((size_t)l1 * 30 + f) * HDD + h2 * DKD;
    const float* qsh = qs + h2 * DKD;
    float acc = 0.f;
    #pragma unroll
    for (int dd = 0; dd < 32; ++dd) acc += (qsh[dd] + rp[dd]) * wr[dd];
    wbN[((size_t)bid * NHEAD + h2) * 32 + f] = acc;
  }
}

extern "C" void kernel_launch(void* const* d_in, const int* in_sizes, int n_in,
                              void* d_out, int out_size, void* d_ws, size_t ws_size,
                              hipStream_t stream) {
  (void)in_sizes; (void)n_in; (void)ws_size; (void)out_size;
  const float* x_skip    = (const float*)d_in[0];
  const float* attention = (const float*)d_in[1];
  const float* ln1_g = (const float*)d_in[2];
  const float* ln1_b = (const float*)d_in[3];
  const float* Wq    = (const float*)d_in[4];
  const float* Wk    = (const float*)d_in[5];
  const float* Wv    = (const float*)d_in[6];
  const float* Wrel  = (const float*)d_in[7];
  const float* rcb   = (const float*)d_in[8];
  const float* rpb   = (const float*)d_in[9];
  const float* Wo    = (const float*)d_in[10];
  const float* bo    = (const float*)d_in[11];
  const float* ln2_g = (const float*)d_in[12];
  const float* ln2_b = (const float*)d_in[13];
  const float* W1    = (const float*)d_in[14];
  const float* b1    = (const float*)d_in[15];
  const float* W2    = (const float*)d_in[16];
  const float* b2    = (const float*)d_in[17];
  float* out = (float*)d_out;
  char* ws = (char*)d_ws;

  unsigned char* E16 = (unsigned char*)(ws + 0);      // 45000*32 = 1,440,000
  int*      idx   = (int*)(ws + 1441792);             // 4,096
  float*    emb   = (float*)(ws + 1445888);           // 131,072
  float*    qcA   = (float*)(ws + 1576960);           // 524,288
  unsigned short* kbTA = (unsigned short*)(ws + 2101248); // 262,144
  unsigned short* vTA  = (unsigned short*)(ws + 2363392); // 262,144
  float*    wbA   = (float*)(ws + 2625536);           // 524,288
  unsigned short* kbTB = (unsigned short*)(ws + 3149824); // 262,144
  unsigned short* vTB  = (unsigned short*)(ws + 3411968); // 262,144
  int*      hist  = (int*)(ws + 3674112);             // 1,048,576
  int*      cnt   = (int*)(ws + 4722688);             // 16
  unsigned long long* cand = (unsigned long long*)(ws + 4722720); // 65,536
  unsigned* chsel = (unsigned*)(ws + 4788256);        // 4,096 -> ends 4,792,352
  float*    qcB   = (float*)(ws + 4792352);           // 524,288
  float*    wbB   = (float*)(ws + 5316640);           // 524,288 -> ends 5,840,928

  hipMemsetAsync(ws + 3674112, 0, 1048576 + 32, stream);   // hist + cnt
  prep_kernel<<<ETB + 4 * TKB, 256, 0, stream>>>(attention, E16, hist, out);
  topk_collect_kernel<<<4 * TKB, 256, 0, stream>>>(attention, hist, cand, cnt);
  topk_sort_kernel<<<4, 1024, 0, stream>>>(cand, cnt, chsel);
  topk_merge_kernel<<<2, 512, 0, stream>>>(chsel, idx);
  gqkv0_kernel<<<1024, 128, 0, stream>>>(x_skip, idx, ln1_g, ln1_b, Wq, Wk, Wv,
                                         Wrel, rcb, rpb, emb, qcA, kbTA, vTA, wbA);
  for (int l = 0; l < 4; ++l) {
    const float* qcI = (l & 1) ? qcB : qcA;
    const unsigned short* kbI = (l & 1) ? kbTB : kbTA;
    const unsigned short* vI  = (l & 1) ? vTB : vTA;
    const float* wbI = (l & 1) ? wbB : wbA;
    float* qcO = (l & 1) ? qcA : qcB;
    unsigned short* kbO = (l & 1) ? kbTA : kbTB;
    unsigned short* vO  = (l & 1) ? vTA : vTB;
    float* wbO = (l & 1) ? wbA : wbB;
    layer_kernel<<<1024, 256, 0, stream>>>(qcI, kbI, vI, wbI, E16, idx,
                                           Wo, bo, ln2_g, ln2_b, W1, b1, W2, b2,
                                           ln1_g, ln1_b, Wq, Wk, Wv, Wrel, rcb,
                                           rpb, emb, qcO, kbO, vO, wbO, out, l);
  }
}

// Round 9
// 317.394 us; speedup vs baseline: 1.6707x; 1.0020x over previous
//
#include <hip/hip_runtime.h>
#include <math.h>

#define SEQL   45000
#define NBAT   2
#define CCH    32
#define NSEL   512
#define NHEAD  4
#define DKD    32
#define HDD    128
#define MLPD   512
#define CDCAP  2048
#define TKB    32     // scan slices per (b,channel)
#define ETB    176    // etab blocks = ceil(45000/256)

// bf16 helpers: round-to-nearest-even pack, cheap unpack (<<16)
__device__ __forceinline__ unsigned short f2bf(float x) {
  unsigned u = __float_as_uint(x);
  u = (u + 0x7fffu + ((u >> 16) & 1u)) >> 16;
  return (unsigned short)u;
}
#define BFL(u) __uint_as_float((u) << 16)
#define BFH(u) __uint_as_float((u) & 0xffff0000u)

// ---------------- K0: E16 build (packed bf16 pairs, 32B/row) + hist + zero --
__global__ __launch_bounds__(256) void prep_kernel(const float* __restrict__ att,
                                                   unsigned char* __restrict__ E16,
                                                   int* __restrict__ hist,
                                                   float* __restrict__ out) {
  {
    int nthr = gridDim.x * 256;
    int gt = blockIdx.x * 256 + threadIdx.x;
    float4 z4 = make_float4(0.f, 0.f, 0.f, 0.f);
    float4* o4 = (float4*)out;
    for (int i = gt; i < NBAT * CCH * SEQL / 4; i += nthr) o4[i] = z4;
  }
  if (blockIdx.x < ETB) {
    int a = blockIdx.x * 256 + threadIdx.x;
    if (a >= SEQL) return;
    float ad = (float)a;
    float outv[16];
    float log2S = log2f((float)SEQL);
    #pragma unroll
    for (int k = 0; k < 5; ++k) {
      float hl = exp2f(3.0f + (float)k * (log2S - 3.0f) * 0.25f);
      outv[k] = exp2f(-ad / hl);
    }
    const int cw[5] = {1, 3, 7, 15, 31};
    #pragma unroll
    for (int k = 0; k < 5; ++k) outv[5 + k] = (a < cw[k]) ? 1.0f : 0.0f;
    float pmax = 0.0f;
    float pk[5];
    #pragma unroll
    for (int k = 0; k < 5; ++k) {
      float mean = 9000.0f * (float)(k + 1);
      float sd = 4500.0f;
      float cc = (mean / sd) * (mean / sd);      // 4,16,36,64,100
      float rr = mean / (sd * sd);
      float logz = lgammaf(cc) - cc * logf(rr);
      float pp;
      if (a == 0) pp = 1e-8f;                    // xlogy -> -inf -> exp = 0
      else pp = expf((cc - 1.0f) * logf(ad) - rr * ad - logz) + 1e-8f;
      pk[k] = pp;
      float mstar = (cc - 1.0f) / rr;            // 6750..44550, interior mode
      float m0 = floorf(mstar), m1 = m0 + 1.0f;
      if (m1 > (float)(SEQL - 1)) m1 = (float)(SEQL - 1);
      float p0 = expf((cc - 1.0f) * logf(m0) - rr * m0 - logz) + 1e-8f;
      float p1 = expf((cc - 1.0f) * logf(m1) - rr * m1 - logz) + 1e-8f;
      pmax = fmaxf(pmax, fmaxf(p0, p1));
    }
    #pragma unroll
    for (int k = 0; k < 5; ++k) outv[10 + k] = pk[k] / pmax;
    outv[15] = 0.0f;
    unsigned by[16];
    #pragma unroll
    for (int k = 0; k < 15; ++k)
      by[k] = (unsigned)(fminf(fmaxf(outv[k], 0.f), 1.f) * 255.f + 0.5f);
    by[15] = 0u;
    // pack as bf16 pairs (integers 0..255 are exact in bf16)
    unsigned pw[8];
    #pragma unroll
    for (int k = 0; k < 8; ++k)
      pw[k] = (unsigned)f2bf((float)by[2 * k]) |
              ((unsigned)f2bf((float)by[2 * k + 1]) << 16);
    uint4 o0 = make_uint4(pw[0], pw[1], pw[2], pw[3]);
    uint4 o1 = make_uint4(pw[4], pw[5], pw[6], pw[7]);
    uint4* dst = (uint4*)(E16 + (size_t)a * 32);
    dst[0] = o0;
    dst[1] = o1;
  } else {
    int bid = blockIdx.x - ETB;
    int ch4 = bid / TKB;
    int blk = bid % TKB;
    int b = ch4 >> 1, ch = ch4 & 1;
    const float* row = att + ((size_t)b * 3 + 1 + ch) * SEQL;
    int* h = hist + (size_t)ch4 * 65536;
    int per = (SEQL + TKB - 1) / TKB;
    int lo = blk * per;
    int hi = lo + per; if (hi > SEQL) hi = SEQL;
    for (int i = lo + threadIdx.x; i < hi; i += 256)
      atomicAdd(&h[__float_as_uint(row[i]) >> 16], 1);  // vals>=0 -> monotone
  }
}

// ---------------- K1: collect w/ inline threshold (R15 version) -------------
__global__ __launch_bounds__(256) void topk_collect_kernel(
    const float* __restrict__ att, const int* __restrict__ hist,
    unsigned long long* __restrict__ cand, int* __restrict__ cnt) {
  __shared__ int s_scan[256];
  __shared__ int s_aux[2];
  int tid = threadIdx.x;
  int ch4 = blockIdx.x / TKB;
  int blk = blockIdx.x % TKB;
  const int* h = hist + (size_t)ch4 * 65536;
  {
    int base = tid * 256;
    int sum = 0;
    for (int i = 0; i < 64; ++i) {
      int4 v = ((const int4*)(h + base))[i];
      sum += v.x + v.y + v.z + v.w;
    }
    s_scan[tid] = sum;
  }
  __syncthreads();
  for (int d = 1; d < 256; d <<= 1) {
    int v = s_scan[tid] + ((tid + d < 256) ? s_scan[tid + d] : 0);
    __syncthreads();
    s_scan[tid] = v;
    __syncthreads();
  }
  {
    int sufEx = (tid == 255) ? 0 : s_scan[tid + 1];
    if (s_scan[tid] >= 256 && sufEx < 256) { s_aux[0] = tid; s_aux[1] = 256 - sufEx; }
  }
  __syncthreads();
  int chunk = s_aux[0], want = s_aux[1];
  s_scan[tid] = h[chunk * 256 + tid];
  __syncthreads();
  for (int d = 1; d < 256; d <<= 1) {
    int v = s_scan[tid] + ((tid + d < 256) ? s_scan[tid + d] : 0);
    __syncthreads();
    s_scan[tid] = v;
    __syncthreads();
  }
  {
    int sufEx2 = (tid == 255) ? 0 : s_scan[tid + 1];
    if (s_scan[tid] >= want && sufEx2 < want) s_aux[0] = chunk * 256 + tid;
  }
  __syncthreads();
  unsigned T16 = (unsigned)s_aux[0];
  int b = ch4 >> 1, ch = ch4 & 1;
  const float* row = att + ((size_t)b * 3 + 1 + ch) * SEQL;
  int per = (SEQL + TKB - 1) / TKB;
  int lo = blk * per;
  int hi = lo + per; if (hi > SEQL) hi = SEQL;
  for (int i = lo + tid; i < hi; i += 256) {
    unsigned key = __float_as_uint(row[i]);
    if ((key >> 16) >= T16) {
      int p = atomicAdd(&cnt[ch4], 1);
      if (p < CDCAP)
        cand[(size_t)ch4 * CDCAP + p] =
            ((unsigned long long)key << 32) | (unsigned)(~(unsigned)i);
    }
  }
}

// ---------------- K2a: per-channel desc sort -> top-256 (4 parallel blocks) -
__global__ __launch_bounds__(1024) void topk_sort_kernel(
    const unsigned long long* __restrict__ cand, const int* __restrict__ cnt,
    unsigned* __restrict__ chsel) {
  __shared__ unsigned long long sc[CDCAP];
  int ch4 = blockIdx.x, t = threadIdx.x;
  int n = cnt[ch4]; if (n > CDCAP) n = CDCAP;   // >=256 by construction
  int P = 256;
  while (P < n) P <<= 1;                        // typical 512
  for (int i = t; i < P; i += 1024)
    sc[i] = (i < n) ? cand[(size_t)ch4 * CDCAP + i] : 0ull;  // 0 sorts last
  __syncthreads();
  for (int k = 2; k <= P; k <<= 1) {
    for (int j = k >> 1; j > 0; j >>= 1) {
      for (int i = t; i < P; i += 1024) {
        int ixj = i ^ j;
        if (ixj > i) {
          unsigned long long va = sc[i], vb2 = sc[ixj];
          bool up = ((i & k) == 0);
          if ((va < vb2) == up) { sc[i] = vb2; sc[ixj] = va; }
        }
      }
      __syncthreads();
    }
  }
  // desc u64 = value desc, tie -> larger ~i = smaller index first
  if (t < 256)
    chsel[(size_t)ch4 * 256 + t] = ~(unsigned)(sc[t] & 0xFFFFFFFFull);
}

// ---------------- K2b: merge acc+don, ascending sort of 512 -----------------
__global__ __launch_bounds__(512) void topk_merge_kernel(const unsigned* __restrict__ chsel,
                                                         int* __restrict__ idx) {
  __shared__ int m[512];
  int b = blockIdx.x, tid = threadIdx.x;
  m[tid] = (int)chsel[(size_t)b * 512 + tid];
  __syncthreads();
  for (int k = 2; k <= 512; k <<= 1) {
    for (int j = k >> 1; j > 0; j >>= 1) {
      int ixj = tid ^ j;
      if (ixj > tid) {
        int va = m[tid], vb2 = m[ixj];
        bool up = ((tid & k) == 0);
        if ((va > vb2) == up) { m[tid] = vb2; m[ixj] = va; }
      }
      __syncthreads();
    }
  }
  idx[b * 512 + tid] = m[tid];
}

// ---------------- K3: fused gather + LN1 + QKV layer 0 ----------------------
// kbT/vT layout (bf16): [((b*4+h)*4+dpack)*4096 + i*8 + (d&7)]
__global__ __launch_bounds__(128) void gqkv0_kernel(
    const float* __restrict__ x, const int* __restrict__ idx,
    const float* __restrict__ ln_g, const float* __restrict__ ln_b,
    const float* __restrict__ Wq, const float* __restrict__ Wk,
    const float* __restrict__ Wv, const float* __restrict__ Wrel,
    const float* __restrict__ rcb, const float* __restrict__ rpb,
    float* __restrict__ emb, float* __restrict__ qc,
    unsigned short* __restrict__ kbT, unsigned short* __restrict__ vT,
    float* __restrict__ wb) {
  __shared__ float qs[128];
  const int l = 0;
  int hd = threadIdx.x;        // 0..127
  int hh = hd >> 5, d = hd & 31;
  int row = blockIdx.x;        // b*512 + i
  int b = row >> 9, ii = row & 511;
  int li = idx[b * NSEL + ii];
  float h[32];
  float mu = 0.f;
  #pragma unroll
  for (int c = 0; c < 32; ++c) {
    h[c] = x[((size_t)b * CCH + c) * SEQL + li];
    mu += h[c];
  }
  if (hd < 32) emb[(size_t)row * CCH + hd] = h[hd];
  mu *= (1.0f / 32.0f);
  float var = 0.f;
  #pragma unroll
  for (int c = 0; c < 32; ++c) { float dd0 = h[c] - mu; var += dd0 * dd0; }
  var *= (1.0f / 32.0f);
  float rstd = rsqrtf(var + 1e-5f);
  const float* g = ln_g + l * CCH;
  const float* bb = ln_b + l * CCH;
  #pragma unroll
  for (int c = 0; c < 32; ++c) h[c] = (h[c] - mu) * rstd * g[c] + bb[c];
  const float* wq = Wq + (size_t)l * CCH * HDD + hd;
  const float* wk = Wk + (size_t)l * CCH * HDD + hd;
  const float* wv = Wv + (size_t)l * CCH * HDD + hd;
  float q = 0.f, kk = 0.f, vv = 0.f;
  #pragma unroll
  for (int c = 0; c < 32; ++c) {
    q += h[c] * wq[c * HDD];
    kk += h[c] * wk[c * HDD];
    vv += h[c] * wv[c * HDD];
  }
  q *= 0.17677669529663687f;   // DK^-0.5
  qs[hd] = q;
  qc[(size_t)row * HDD + hd] = q + rcb[(l * NHEAD + hh) * DKD + d];
  size_t tpos = ((size_t)(b * 4 + hh) * 4 + (d >> 3)) * 4096 + (size_t)ii * 8 + (d & 7);
  kbT[tpos] = f2bf(kk);
  vT[tpos]  = f2bf(vv);
  __syncthreads();
  if (hd < 120) {
    int h2 = hd / 30, f = hd % 30;
    const float* wr = Wrel + ((size_t)l * 30 + f) * HDD + h2 * DKD;
    const float* rp = rpb + (l * NHEAD + h2) * DKD;
    const float* qsh = qs + h2 * DKD;
    float acc = 0.f;
    #pragma unroll
    for (int dd = 0; dd < 32; ++dd) acc += (qsh[dd] + rp[dd]) * wr[dd];
    wb[((size_t)row * NHEAD + h2) * 32 + f] = acc;   // padded stride 32
  }
}

// ---------------- K4: fused layer = attn + proj/LN2/MLP + qkv(l+1) ----------
// R21: R17 structure exactly (298us verified: 256 thr, (256,4), es j-major
// uint4, 64 VGPR no spill). One change: multi-accumulator inner loops.
// QK was a 32-FMA serial chain into one cacc (~128cyc dep path per u-iter);
// now 4 per-dp accumulators. rel r0/r1 split into a/b halves. FP reassoc
// only — absmax headroom 0.0156 vs 0.0875. VGPR headroom: cap 128 @ this
// occupancy, compiler was at 64.
__global__ __launch_bounds__(256, 4) void layer_kernel(
    const float* __restrict__ qc, const unsigned short* __restrict__ kbT,
    const unsigned short* __restrict__ vT, const float* __restrict__ wbuf,
    const unsigned char* __restrict__ E16, const int* __restrict__ idx,
    const float* __restrict__ Wo, const float* __restrict__ bo,
    const float* __restrict__ ln2_g, const float* __restrict__ ln2_b,
    const float* __restrict__ W1, const float* __restrict__ b1,
    const float* __restrict__ W2, const float* __restrict__ b2,
    const float* __restrict__ ln1_g, const float* __restrict__ ln1_b,
    const float* __restrict__ Wq, const float* __restrict__ Wk,
    const float* __restrict__ Wv, const float* __restrict__ Wrel,
    const float* __restrict__ rcb, const float* __restrict__ rpb,
    float* __restrict__ emb, float* __restrict__ qcN,
    unsigned short* __restrict__ kbTN, unsigned short* __restrict__ vTN,
    float* __restrict__ wbN, float* __restrict__ out, int layer) {
  __shared__ unsigned esb[8 * 512]; // 16KB j-major: esb[j*8+p] = bf16 pair (feat 2p, 2p+1); [j*8+7] hi = sign
  __shared__ float obs[128];        // attn output row (LDS-resident)
  __shared__ float part[8][32];
  __shared__ float res[32];
  __shared__ float hln[32];
  __shared__ float fin[32];
  __shared__ float a1s[MLPD];
  __shared__ float qs[128];
  int bid = blockIdx.x;
  int b = bid >> 9;
  int i = bid & 511;
  int tid = threadIdx.x;
  int pos = idx[b * NSEL + i];     // this row's sequence position
  // ---- E-row fetch once per block into LDS (head-shared, pre-packed) ----
  #pragma unroll
  for (int rep = 0; rep < 2; ++rep) {
    int j = tid + rep * 256;
    int dj = pos - idx[b * NSEL + j];
    int a = dj < 0 ? -dj : dj;
    const uint4* eg = (const uint4*)(E16 + (size_t)a * 32);
    uint4 e0 = eg[0];
    uint4 e1 = eg[1];
    unsigned sc = dj > 0 ? 0x3F80u : (dj < 0 ? 0xBF80u : 0u);  // bf16(sign)
    e1.w |= (sc << 16);
    uint4* ed = (uint4*)(esb + j * 8);
    ed[0] = e0;
    ed[1] = e1;
  }
  __syncthreads();
  // ---- attention: wave = head ----
  {
    int h = tid >> 6, ln = tid & 63;
    const float* qrow = qc + (size_t)(b * NSEL + i) * HDD + h * DKD;
    float q[32];
    #pragma unroll
    for (int d4 = 0; d4 < 8; ++d4) {
      float4 qv = *(const float4*)(qrow + d4 * 4);
      q[d4 * 4 + 0] = qv.x; q[d4 * 4 + 1] = qv.y;
      q[d4 * 4 + 2] = qv.z; q[d4 * 4 + 3] = qv.w;
    }
    const float* wrow = wbuf + ((size_t)(b * NSEL + i) * NHEAD + h) * 32;
    float w0[15], w1[15];
    #pragma unroll
    for (int f = 0; f < 15; ++f) {
      w0[f] = wrow[f] * (1.0f / 255.0f);        // u8 scale folded in
      w1[f] = wrow[15 + f] * (1.0f / 255.0f);
    }
    const uint4* kb4 = (const uint4*)kbT + (size_t)(b * 4 + h) * 4 * 512;
    const uint4* vb4 = (const uint4*)vT + (size_t)(b * 4 + h) * 4 * 512;
    float lg[8];
    #pragma unroll
    for (int u = 0; u < 8; ++u) {
      int j = u * 64 + ln;
      // 4 independent accumulators (one per dp) — cuts the 32-FMA serial
      // chain to 4x 8-FMA chains
      float ca0, ca1, ca2, ca3;
      {
        uint4 kv = kb4[0 * 512 + j];
        ca0  = q[0] * BFL(kv.x) + q[1] * BFH(kv.x)
             + q[2] * BFL(kv.y) + q[3] * BFH(kv.y)
             + q[4] * BFL(kv.z) + q[5] * BFH(kv.z)
             + q[6] * BFL(kv.w) + q[7] * BFH(kv.w);
      }
      {
        uint4 kv = kb4[1 * 512 + j];
        ca1  = q[8]  * BFL(kv.x) + q[9]  * BFH(kv.x)
             + q[10] * BFL(kv.y) + q[11] * BFH(kv.y)
             + q[12] * BFL(kv.z) + q[13] * BFH(kv.z)
             + q[14] * BFL(kv.w) + q[15] * BFH(kv.w);
      }
      {
        uint4 kv = kb4[2 * 512 + j];
        ca2  = q[16] * BFL(kv.x) + q[17] * BFH(kv.x)
             + q[18] * BFL(kv.y) + q[19] * BFH(kv.y)
             + q[20] * BFL(kv.z) + q[21] * BFH(kv.z)
             + q[22] * BFL(kv.w) + q[23] * BFH(kv.w);
      }
      {
        uint4 kv = kb4[3 * 512 + j];
        ca3  = q[24] * BFL(kv.x) + q[25] * BFH(kv.x)
             + q[26] * BFL(kv.y) + q[27] * BFH(kv.y)
             + q[28] * BFL(kv.z) + q[29] * BFH(kv.z)
             + q[30] * BFL(kv.w) + q[31] * BFH(kv.w);
      }
      const uint4* ej = (const uint4*)(esb + j * 8);
      uint4 a0 = ej[0];
      uint4 a1 = ej[1];
      // r0/r1 split into a/b halves (two independent chains each)
      float r0a, r0b, r1a, r1b;
      r0a  = BFL(a0.x) * w0[0]  + BFH(a0.x) * w0[1];
      r1a  = BFL(a0.x) * w1[0]  + BFH(a0.x) * w1[1];
      r0a += BFL(a0.y) * w0[2]  + BFH(a0.y) * w0[3];
      r1a += BFL(a0.y) * w1[2]  + BFH(a0.y) * w1[3];
      r0a += BFL(a0.z) * w0[4]  + BFH(a0.z) * w0[5];
      r1a += BFL(a0.z) * w1[4]  + BFH(a0.z) * w1[5];
      r0a += BFL(a0.w) * w0[6]  + BFH(a0.w) * w0[7];
      r1a += BFL(a0.w) * w1[6]  + BFH(a0.w) * w1[7];
      r0b  = BFL(a1.x) * w0[8]  + BFH(a1.x) * w0[9];
      r1b  = BFL(a1.x) * w1[8]  + BFH(a1.x) * w1[9];
      r0b += BFL(a1.y) * w0[10] + BFH(a1.y) * w0[11];
      r1b += BFL(a1.y) * w1[10] + BFH(a1.y) * w1[11];
      r0b += BFL(a1.z) * w0[12] + BFH(a1.z) * w0[13];
      r1b += BFL(a1.z) * w1[12] + BFH(a1.z) * w1[13];
      r0b += BFL(a1.w) * w0[14];
      r1b += BFL(a1.w) * w1[14];
      lg[u] = ((ca0 + ca1) + (ca2 + ca3)) + (r0a + r0b)
            + BFH(a1.w) * (r1a + r1b);
    }
    // full-row softmax across the wave (512 logits, 8/lane), in registers
    float m = lg[0];
    #pragma unroll
    for (int u = 1; u < 8; ++u) m = fmaxf(m, lg[u]);
    #pragma unroll
    for (int s = 1; s < 64; s <<= 1) m = fmaxf(m, __shfl_xor(m, s));
    float ssum = 0.f;
    #pragma unroll
    for (int u = 0; u < 8; ++u) { lg[u] = __expf(lg[u] - m); ssum += lg[u]; }
    #pragma unroll
    for (int s = 1; s < 64; s <<= 1) ssum += __shfl_xor(ssum, s);
    float invs = 1.0f / ssum;
    // PV: p in registers, v coalesced; reduced-shuffle epilogue -> LDS obs
    #pragma unroll
    for (int dp = 0; dp < 4; ++dp) {
      float acc[8] = {0.f, 0.f, 0.f, 0.f, 0.f, 0.f, 0.f, 0.f};
      #pragma unroll
      for (int u = 0; u < 8; ++u) {
        uint4 vv = vb4[dp * 512 + u * 64 + ln];
        float p = lg[u];
        acc[0] += p * BFL(vv.x); acc[1] += p * BFH(vv.x);
        acc[2] += p * BFL(vv.y); acc[3] += p * BFH(vv.y);
        acc[4] += p * BFL(vv.z); acc[5] += p * BFH(vv.z);
        acc[6] += p * BFL(vv.w); acc[7] += p * BFH(vv.w);
      }
      #pragma unroll
      for (int s = 1; s < 8; s <<= 1) {
        #pragma unroll
        for (int t = 0; t < 8; ++t) acc[t] += __shfl_xor(acc[t], s);
      }
      int sel = ln & 7;
      float y = acc[0];
      #pragma unroll
      for (int t = 1; t < 8; ++t) y = (sel == t) ? acc[t] : y;
      #pragma unroll
      for (int s = 8; s < 64; s <<= 1) y += __shfl_xor(y, s);
      if (ln < 8) obs[h * DKD + dp * 8 + ln] = y * invs;
    }
  }
  __syncthreads();
  // ---- proj + residual + LN2 + MLP + residual ----
  int c = tid & 31, seg = tid >> 5;
  {
    const float* wo = Wo + (size_t)layer * HDD * CCH + c;
    float pacc = 0.f;
    #pragma unroll
    for (int k = 0; k < 16; ++k) {
      int kk = seg * 16 + k;
      pacc += obs[kk] * wo[kk * CCH];
    }
    part[seg][c] = pacc;
  }
  __syncthreads();
  if (tid < 32) {
    float s = bo[layer * CCH + tid] + emb[(size_t)bid * CCH + tid];
    #pragma unroll
    for (int sg = 0; sg < 8; ++sg) s += part[sg][tid];
    res[tid] = s;
  }
  __syncthreads();
  if (tid < 32) {
    float mu = 0.f, s2 = 0.f;
    #pragma unroll
    for (int c2 = 0; c2 < 32; ++c2) { float v = res[c2]; mu += v; s2 += v * v; }
    mu *= (1.0f / 32.0f);
    float var = s2 * (1.0f / 32.0f) - mu * mu;
    float rstd = rsqrtf(var + 1e-5f);
    hln[tid] = (res[tid] - mu) * rstd * ln2_g[layer * CCH + tid] + ln2_b[layer * CCH + tid];
  }
  __syncthreads();
  {
    const float* w1 = W1 + (size_t)layer * CCH * MLPD;
    float accA = b1[layer * MLPD + tid];
    float accB = b1[layer * MLPD + tid + 256];
    for (int c2 = 0; c2 < 32; ++c2) {
      float hv = hln[c2];
      accA += hv * w1[c2 * MLPD + tid];
      accB += hv * w1[c2 * MLPD + tid + 256];
    }
    a1s[tid]       = 0.5f * accA * (1.0f + erff(accA * 0.70710678118654752f));
    a1s[tid + 256] = 0.5f * accB * (1.0f + erff(accB * 0.70710678118654752f));
  }
  __syncthreads();
  {
    const float* w2 = W2 + (size_t)layer * MLPD * CCH;
    float acc2 = 0.f;
    #pragma unroll 4
    for (int mi = 0; mi < 64; ++mi) {
      int m = seg * 64 + mi;
      acc2 += a1s[m] * w2[m * CCH + c];
    }
    __syncthreads();                    // part[] reuse
    part[seg][c] = acc2;
  }
  __syncthreads();
  if (tid < 32) {
    float s = b2[layer * CCH + tid] + res[tid];
    #pragma unroll
    for (int sg = 0; sg < 8; ++sg) s += part[sg][tid];
    fin[tid] = s;
    if (layer < 3) emb[(size_t)bid * CCH + tid] = s;
  }
  __syncthreads();
  if (layer == 3) {
    if (tid < 32) out[((size_t)b * CCH + tid) * SEQL + pos] = fin[tid];
    return;
  }
  // ---- qkv for layer l+1 (into the ping-pong "next" buffers) ----
  const int l1 = layer + 1;
  bool act = tid < 128;
  int hd = tid & 127;
  int hh2 = hd >> 5, dd2 = hd & 31;
  if (act) {
    float hx[32];
    float mu = 0.f;
    #pragma unroll
    for (int c2 = 0; c2 < 32; ++c2) { hx[c2] = fin[c2]; mu += hx[c2]; }
    mu *= (1.0f / 32.0f);
    float var = 0.f;
    #pragma unroll
    for (int c2 = 0; c2 < 32; ++c2) { float dd = hx[c2] - mu; var += dd * dd; }
    var *= (1.0f / 32.0f);
    float rstd = rsqrtf(var + 1e-5f);
    const float* g = ln1_g + l1 * CCH;
    const float* bb = ln1_b + l1 * CCH;
    #pragma unroll
    for (int c2 = 0; c2 < 32; ++c2) hx[c2] = (hx[c2] - mu) * rstd * g[c2] + bb[c2];
    const float* wq = Wq + (size_t)l1 * CCH * HDD + hd;
    const float* wk = Wk + (size_t)l1 * CCH * HDD + hd;
    const float* wv = Wv + (size_t)l1 * CCH * HDD + hd;
    float q = 0.f, kk = 0.f, vv = 0.f;
    #pragma unroll
    for (int c2 = 0; c2 < 32; ++c2) {
      q += hx[c2] * wq[c2 * HDD];
      kk += hx[c2] * wk[c2 * HDD];
      vv += hx[c2] * wv[c2 * HDD];
    }
    q *= 0.17677669529663687f;
    qs[hd] = q;
    qcN[(size_t)bid * HDD + hd] = q + rcb[(l1 * NHEAD + hh2) * DKD + dd2];
    size_t tpos = ((size_t)(b * 4 + hh2) * 4 + (dd2 >> 3)) * 4096 + (size_t)i * 8 + (dd2 & 7);
    kbTN[tpos] = f2bf(kk);
    vTN[tpos]  = f2bf(vv);
  }
  __syncthreads();
  if (act && hd < 120) {
    int h2 = hd / 30, f = hd % 30;
    const float* rp = rpb + (l1 * NHEAD + h2) * DKD;
    const float* wr = Wrel + ((size_t)l1 * 30 + f) * HDD + h2 * DKD;
    const float* qsh = qs + h2 * DKD;
    float acc = 0.f;
    #pragma unroll
    for (int dd = 0; dd < 32; ++dd) acc += (qsh[dd] + rp[dd]) * wr[dd];
    wbN[((size_t)bid * NHEAD + h2) * 32 + f] = acc;
  }
}

extern "C" void kernel_launch(void* const* d_in, const int* in_sizes, int n_in,
                              void* d_out, int out_size, void* d_ws, size_t ws_size,
                              hipStream_t stream) {
  (void)in_sizes; (void)n_in; (void)ws_size; (void)out_size;
  const float* x_skip    = (const float*)d_in[0];
  const float* attention = (const float*)d_in[1];
  const float* ln1_g = (const float*)d_in[2];
  const float* ln1_b = (const float*)d_in[3];
  const float* Wq    = (const float*)d_in[4];
  const float* Wk    = (const float*)d_in[5];
  const float* Wv    = (const float*)d_in[6];
  const float* Wrel  = (const float*)d_in[7];
  const float* rcb   = (const float*)d_in[8];
  const float* rpb   = (const float*)d_in[9];
  const float* Wo    = (const float*)d_in[10];
  const float* bo    = (const float*)d_in[11];
  const float* ln2_g = (const float*)d_in[12];
  const float* ln2_b = (const float*)d_in[13];
  const float* W1    = (const float*)d_in[14];
  const float* b1    = (const float*)d_in[15];
  const float* W2    = (const float*)d_in[16];
  const float* b2    = (const float*)d_in[17];
  float* out = (float*)d_out;
  char* ws = (char*)d_ws;

  unsigned char* E16 = (unsigned char*)(ws + 0);      // 45000*32 = 1,440,000
  int*      idx   = (int*)(ws + 1441792);             // 4,096
  float*    emb   = (float*)(ws + 1445888);           // 131,072
  float*    qcA   = (float*)(ws + 1576960);           // 524,288
  unsigned short* kbTA = (unsigned short*)(ws + 2101248); // 262,144
  unsigned short* vTA  = (unsigned short*)(ws + 2363392); // 262,144
  float*    wbA   = (float*)(ws + 2625536);           // 524,288
  unsigned short* kbTB = (unsigned short*)(ws + 3149824); // 262,144
  unsigned short* vTB  = (unsigned short*)(ws + 3411968); // 262,144
  int*      hist  = (int*)(ws + 3674112);             // 1,048,576
  int*      cnt   = (int*)(ws + 4722688);             // 16
  unsigned long long* cand = (unsigned long long*)(ws + 4722720); // 65,536
  unsigned* chsel = (unsigned*)(ws + 4788256);        // 4,096 -> ends 4,792,352
  float*    qcB   = (float*)(ws + 4792352);           // 524,288
  float*    wbB   = (float*)(ws + 5316640);           // 524,288 -> ends 5,840,928

  hipMemsetAsync(ws + 3674112, 0, 1048576 + 32, stream);   // hist + cnt
  prep_kernel<<<ETB + 4 * TKB, 256, 0, stream>>>(attention, E16, hist, out);
  topk_collect_kernel<<<4 * TKB, 256, 0, stream>>>(attention, hist, cand, cnt);
  topk_sort_kernel<<<4, 1024, 0, stream>>>(cand, cnt, chsel);
  topk_merge_kernel<<<2, 512, 0, stream>>>(chsel, idx);
  gqkv0_kernel<<<1024, 128, 0, stream>>>(x_skip, idx, ln1_g, ln1_b, Wq, Wk, Wv,
                                         Wrel, rcb, rpb, emb, qcA, kbTA, vTA, wbA);
  for (int l = 0; l < 4; ++l) {
    const float* qcI = (l & 1) ? qcB : qcA;
    const unsigned short* kbI = (l & 1) ? kbTB : kbTA;
    const unsigned short* vI  = (l & 1) ? vTB : vTA;
    const float* wbI = (l & 1) ? wbB : wbA;
    float* qcO = (l & 1) ? qcA : qcB;
    unsigned short* kbO = (l & 1) ? kbTA : kbTB;
    unsigned short* vO  = (l & 1) ? vTA : vTB;
    float* wbO = (l & 1) ? wbA : wbB;
    layer_kernel<<<1024, 256, 0, stream>>>(qcI, kbI, vI, wbI, E16, idx,
                                           Wo, bo, ln2_g, ln2_b, W1, b1, W2, b2,
                                           ln1_g, ln1_b, Wq, Wk, Wv, Wrel, rcb,
                                           rpb, emb, qcO, kbO, vO, wbO, out, l);
  }
}

// Round 10
// 300.620 us; speedup vs baseline: 1.7639x; 1.0558x over previous
//
#include <hip/hip_runtime.h>
#include <math.h>

#define SEQL   45000
#define NBAT   2
#define CCH    32
#define NSEL   512
#define NHEAD  4
#define DKD    32
#define HDD    128
#define MLPD   512
#define CDCAP  2048
#define ETB    176    // etab blocks = ceil(45000/256)

// bf16 helpers: round-to-nearest-even pack, cheap unpack (<<16)
__device__ __forceinline__ unsigned short f2bf(float x) {
  unsigned u = __float_as_uint(x);
  u = (u + 0x7fffu + ((u >> 16) & 1u)) >> 16;
  return (unsigned short)u;
}
#define BFL(u) __uint_as_float((u) << 16)
#define BFH(u) __uint_as_float((u) & 0xffff0000u)
#define U8F(w, s) ((float)(((w) >> (s)) & 0xffu))

// ---------------- K0: etab build (u8, 16B/row) + d_out zero -----------------
// R22: hist removed entirely (threshold now computed in topk_channel_kernel's
// LDS). prep = out-zero + E-table only.
__global__ __launch_bounds__(256) void prep_kernel(unsigned char* __restrict__ E,
                                                   float* __restrict__ out) {
  {
    int nthr = gridDim.x * 256;
    int gt = blockIdx.x * 256 + threadIdx.x;
    float4 z4 = make_float4(0.f, 0.f, 0.f, 0.f);
    float4* o4 = (float4*)out;
    for (int i = gt; i < NBAT * CCH * SEQL / 4; i += nthr) o4[i] = z4;
  }
  if (blockIdx.x >= ETB) return;
  int a = blockIdx.x * 256 + threadIdx.x;
  if (a >= SEQL) return;
  float ad = (float)a;
  float outv[16];
  float log2S = log2f((float)SEQL);
  #pragma unroll
  for (int k = 0; k < 5; ++k) {
    float hl = exp2f(3.0f + (float)k * (log2S - 3.0f) * 0.25f);
    outv[k] = exp2f(-ad / hl);
  }
  const int cw[5] = {1, 3, 7, 15, 31};
  #pragma unroll
  for (int k = 0; k < 5; ++k) outv[5 + k] = (a < cw[k]) ? 1.0f : 0.0f;
  float pmax = 0.0f;
  float pk[5];
  #pragma unroll
  for (int k = 0; k < 5; ++k) {
    float mean = 9000.0f * (float)(k + 1);
    float sd = 4500.0f;
    float cc = (mean / sd) * (mean / sd);      // 4,16,36,64,100
    float rr = mean / (sd * sd);
    float logz = lgammaf(cc) - cc * logf(rr);
    float pp;
    if (a == 0) pp = 1e-8f;                    // xlogy -> -inf -> exp = 0
    else pp = expf((cc - 1.0f) * logf(ad) - rr * ad - logz) + 1e-8f;
    pk[k] = pp;
    float mstar = (cc - 1.0f) / rr;            // 6750..44550, interior mode
    float m0 = floorf(mstar), m1 = m0 + 1.0f;
    if (m1 > (float)(SEQL - 1)) m1 = (float)(SEQL - 1);
    float p0 = expf((cc - 1.0f) * logf(m0) - rr * m0 - logz) + 1e-8f;
    float p1 = expf((cc - 1.0f) * logf(m1) - rr * m1 - logz) + 1e-8f;
    pmax = fmaxf(pmax, fmaxf(p0, p1));
  }
  #pragma unroll
  for (int k = 0; k < 5; ++k) outv[10 + k] = pk[k] / pmax;
  outv[15] = 0.0f;
  unsigned by[16];
  #pragma unroll
  for (int k = 0; k < 15; ++k)
    by[k] = (unsigned)(fminf(fmaxf(outv[k], 0.f), 1.f) * 255.f + 0.5f);
  by[15] = 0u;
  uint4 o;
  o.x = by[0]  | (by[1]  << 8) | (by[2]  << 16) | (by[3]  << 24);
  o.y = by[4]  | (by[5]  << 8) | (by[6]  << 16) | (by[7]  << 24);
  o.z = by[8]  | (by[9]  << 8) | (by[10] << 16) | (by[11] << 24);
  o.w = by[12] | (by[13] << 8) | (by[14] << 16);
  *(uint4*)(E + (size_t)a * 16) = o;
}

// ---------------- K1: per-channel fused topk (threshold+collect+sort) -------
// R22: one block per channel (4 blocks, 1024 thr). Two-pass 256-bin LDS
// histogram refinement computes the SAME 16-bit threshold as the old global
// 64K-bin scan (level1 = top byte == old chunk; level2 = next byte), then
// collects candidates into LDS and bitonic-sorts desc. Replaces memset+
// global-hist+collect+sort (3 launches, 33MB hist scans, 90K global atomics).
__global__ __launch_bounds__(1024) void topk_channel_kernel(
    const float* __restrict__ att, unsigned* __restrict__ chsel) {
  __shared__ unsigned long long sc[CDCAP];  // 16KB candidates
  __shared__ int hist[256];
  __shared__ int scan[256];
  __shared__ int aux[2];
  __shared__ int cnt;
  int ch4 = blockIdx.x, t = threadIdx.x;
  int b = ch4 >> 1, ch = ch4 & 1;
  const float* row = att + ((size_t)b * 3 + 1 + ch) * SEQL;
  if (t < 256) hist[t] = 0;
  if (t == 0) cnt = 0;
  __syncthreads();
  // pass1: top-byte histogram (vals >= 0 -> bits monotone)
  for (int i = t; i < SEQL; i += 1024)
    atomicAdd(&hist[__float_as_uint(row[i]) >> 24], 1);
  __syncthreads();
  if (t < 256) scan[t] = hist[t];
  __syncthreads();
  for (int d = 1; d < 256; d <<= 1) {
    int v = 0;
    if (t < 256) v = scan[t] + ((t + d < 256) ? scan[t + d] : 0);
    __syncthreads();
    if (t < 256) scan[t] = v;
    __syncthreads();
  }
  if (t < 256) {
    int sufEx = (t == 255) ? 0 : scan[t + 1];
    if (scan[t] >= 256 && sufEx < 256) { aux[0] = t; aux[1] = 256 - sufEx; }
  }
  __syncthreads();
  int B = aux[0], want = aux[1];
  if (t < 256) hist[t] = 0;
  __syncthreads();
  // pass2: second-byte histogram within top byte == B
  for (int i = t; i < SEQL; i += 1024) {
    unsigned key = __float_as_uint(row[i]);
    if ((int)(key >> 24) == B) atomicAdd(&hist[(key >> 16) & 0xffu], 1);
  }
  __syncthreads();
  if (t < 256) scan[t] = hist[t];
  __syncthreads();
  for (int d = 1; d < 256; d <<= 1) {
    int v = 0;
    if (t < 256) v = scan[t] + ((t + d < 256) ? scan[t + d] : 0);
    __syncthreads();
    if (t < 256) scan[t] = v;
    __syncthreads();
  }
  if (t < 256) {
    int sufEx = (t == 255) ? 0 : scan[t + 1];
    if (scan[t] >= want && sufEx < want) aux[0] = (B << 8) | t;
  }
  __syncthreads();
  unsigned T16 = (unsigned)aux[0];
  // pass3: collect all keys with high16 >= T16 (count in [256, ~2048])
  for (int i = t; i < SEQL; i += 1024) {
    unsigned key = __float_as_uint(row[i]);
    if ((key >> 16) >= T16) {
      int p = atomicAdd(&cnt, 1);
      if (p < CDCAP)
        sc[p] = ((unsigned long long)key << 32) | (unsigned)(~(unsigned)i);
    }
  }
  __syncthreads();
  int n = cnt; if (n > CDCAP) n = CDCAP;
  int P = 256;
  while (P < n) P <<= 1;                      // typical 512
  for (int i2 = t; i2 < P; i2 += 1024)
    if (i2 >= n) sc[i2] = 0ull;               // 0 sorts last
  __syncthreads();
  for (int k = 2; k <= P; k <<= 1) {
    for (int j = k >> 1; j > 0; j >>= 1) {
      for (int i2 = t; i2 < P; i2 += 1024) {
        int ixj = i2 ^ j;
        if (ixj > i2) {
          unsigned long long va = sc[i2], vb2 = sc[ixj];
          bool up = ((i2 & k) == 0);
          if ((va < vb2) == up) { sc[i2] = vb2; sc[ixj] = va; }
        }
      }
      __syncthreads();
    }
  }
  // desc u64 = value desc, tie -> larger ~i = smaller index first
  if (t < 256)
    chsel[(size_t)ch4 * 256 + t] = ~(unsigned)(sc[t] & 0xFFFFFFFFull);
}

// ---------------- K2: merge acc+don, ascending sort of 512 ------------------
__global__ __launch_bounds__(512) void topk_merge_kernel(const unsigned* __restrict__ chsel,
                                                         int* __restrict__ idx) {
  __shared__ int m[512];
  int b = blockIdx.x, tid = threadIdx.x;
  m[tid] = (int)chsel[(size_t)b * 512 + tid];
  __syncthreads();
  for (int k = 2; k <= 512; k <<= 1) {
    for (int j = k >> 1; j > 0; j >>= 1) {
      int ixj = tid ^ j;
      if (ixj > tid) {
        int va = m[tid], vb2 = m[ixj];
        bool up = ((tid & k) == 0);
        if ((va > vb2) == up) { m[tid] = vb2; m[ixj] = va; }
      }
      __syncthreads();
    }
  }
  idx[b * 512 + tid] = m[tid];
}

// ---------------- K3: fused gather + LN1 + QKV layer 0 ----------------------
// kbT/vT layout (bf16): [((b*4+h)*4+dpack)*4096 + i*8 + (d&7)]
__global__ __launch_bounds__(128) void gqkv0_kernel(
    const float* __restrict__ x, const int* __restrict__ idx,
    const float* __restrict__ ln_g, const float* __restrict__ ln_b,
    const float* __restrict__ Wq, const float* __restrict__ Wk,
    const float* __restrict__ Wv, const float* __restrict__ Wrel,
    const float* __restrict__ rcb, const float* __restrict__ rpb,
    float* __restrict__ emb, float* __restrict__ qc,
    unsigned short* __restrict__ kbT, unsigned short* __restrict__ vT,
    float* __restrict__ wb) {
  __shared__ float qs[128];
  const int l = 0;
  int hd = threadIdx.x;        // 0..127
  int hh = hd >> 5, d = hd & 31;
  int row = blockIdx.x;        // b*512 + i
  int b = row >> 9, ii = row & 511;
  int li = idx[b * NSEL + ii];
  float h[32];
  float mu = 0.f;
  #pragma unroll
  for (int c = 0; c < 32; ++c) {
    h[c] = x[((size_t)b * CCH + c) * SEQL + li];
    mu += h[c];
  }
  if (hd < 32) emb[(size_t)row * CCH + hd] = h[hd];
  mu *= (1.0f / 32.0f);
  float var = 0.f;
  #pragma unroll
  for (int c = 0; c < 32; ++c) { float dd0 = h[c] - mu; var += dd0 * dd0; }
  var *= (1.0f / 32.0f);
  float rstd = rsqrtf(var + 1e-5f);
  const float* g = ln_g + l * CCH;
  const float* bb = ln_b + l * CCH;
  #pragma unroll
  for (int c = 0; c < 32; ++c) h[c] = (h[c] - mu) * rstd * g[c] + bb[c];
  const float* wq = Wq + (size_t)l * CCH * HDD + hd;
  const float* wk = Wk + (size_t)l * CCH * HDD + hd;
  const float* wv = Wv + (size_t)l * CCH * HDD + hd;
  float q = 0.f, kk = 0.f, vv = 0.f;
  #pragma unroll
  for (int c = 0; c < 32; ++c) {
    q += h[c] * wq[c * HDD];
    kk += h[c] * wk[c * HDD];
    vv += h[c] * wv[c * HDD];
  }
  q *= 0.17677669529663687f;   // DK^-0.5
  qs[hd] = q;
  qc[(size_t)row * HDD + hd] = q + rcb[(l * NHEAD + hh) * DKD + d];
  size_t tpos = ((size_t)(b * 4 + hh) * 4 + (d >> 3)) * 4096 + (size_t)ii * 8 + (d & 7);
  kbT[tpos] = f2bf(kk);
  vT[tpos]  = f2bf(vv);
  __syncthreads();
  if (hd < 120) {
    int h2 = hd / 30, f = hd % 30;
    const float* wr = Wrel + ((size_t)l * 30 + f) * HDD + h2 * DKD;
    const float* rp = rpb + (l * NHEAD + h2) * DKD;
    const float* qsh = qs + h2 * DKD;
    float acc = 0.f;
    #pragma unroll
    for (int dd = 0; dd < 32; ++dd) acc += (qsh[dd] + rp[dd]) * wr[dd];
    wb[((size_t)row * NHEAD + h2) * 32 + f] = acc;   // padded stride 32
  }
}

// ---------------- K4: fused layer = attn + proj/LN2/MLP + qkv(l+1) ----------
// R22: measured-best layer body restored (R15/R16: u8 E decode in-layer,
// float2 es2 b64 reads = 41.7us vs 45.5 for the bf16-packed variants).
// LDS ~37.2KB -> 4 blocks/CU at (256,4).
__global__ __launch_bounds__(256, 4) void layer_kernel(
    const float* __restrict__ qc, const unsigned short* __restrict__ kbT,
    const unsigned short* __restrict__ vT, const float* __restrict__ wbuf,
    const unsigned char* __restrict__ E, const int* __restrict__ idx,
    const float* __restrict__ Wo, const float* __restrict__ bo,
    const float* __restrict__ ln2_g, const float* __restrict__ ln2_b,
    const float* __restrict__ W1, const float* __restrict__ b1,
    const float* __restrict__ W2, const float* __restrict__ b2,
    const float* __restrict__ ln1_g, const float* __restrict__ ln1_b,
    const float* __restrict__ Wq, const float* __restrict__ Wk,
    const float* __restrict__ Wv, const float* __restrict__ Wrel,
    const float* __restrict__ rcb, const float* __restrict__ rpb,
    float* __restrict__ emb, float* __restrict__ qcN,
    unsigned short* __restrict__ kbTN, unsigned short* __restrict__ vTN,
    float* __restrict__ wbN, float* __restrict__ out, int layer) {
  __shared__ float2 es2[8 * 512]; // 32KB: es2[f2*512+j] = feats {2f2,2f2+1}; [7].y = sign
  __shared__ float obs[128];      // attn output row (LDS-resident)
  __shared__ float part[8][32];
  __shared__ float res[32];
  __shared__ float hln[32];
  __shared__ float fin[32];
  __shared__ float a1s[MLPD];
  __shared__ float qs[128];
  int bid = blockIdx.x;
  int b = bid >> 9;
  int i = bid & 511;
  int tid = threadIdx.x;
  int pos = idx[b * NSEL + i];     // this row's sequence position
  // ---- E-row decode once per block into LDS (head-shared) ----
  #pragma unroll
  for (int rep = 0; rep < 2; ++rep) {
    int j = tid + rep * 256;
    int dj = pos - idx[b * NSEL + j];
    int a = dj < 0 ? -dj : dj;
    uint4 e = *(const uint4*)(E + (size_t)a * 16);    // one 16B gather/pair
    float sgn = dj > 0 ? 1.f : (dj < 0 ? -1.f : 0.f);
    es2[0 * 512 + j] = make_float2(U8F(e.x, 0),  U8F(e.x, 8));
    es2[1 * 512 + j] = make_float2(U8F(e.x, 16), U8F(e.x, 24));
    es2[2 * 512 + j] = make_float2(U8F(e.y, 0),  U8F(e.y, 8));
    es2[3 * 512 + j] = make_float2(U8F(e.y, 16), U8F(e.y, 24));
    es2[4 * 512 + j] = make_float2(U8F(e.z, 0),  U8F(e.z, 8));
    es2[5 * 512 + j] = make_float2(U8F(e.z, 16), U8F(e.z, 24));
    es2[6 * 512 + j] = make_float2(U8F(e.w, 0),  U8F(e.w, 8));
    es2[7 * 512 + j] = make_float2(U8F(e.w, 16), sgn);
  }
  __syncthreads();
  // ---- attention: wave = head ----
  {
    int h = tid >> 6, ln = tid & 63;
    const float* qrow = qc + (size_t)(b * NSEL + i) * HDD + h * DKD;
    float q[32];
    #pragma unroll
    for (int d4 = 0; d4 < 8; ++d4) {
      float4 qv = *(const float4*)(qrow + d4 * 4);
      q[d4 * 4 + 0] = qv.x; q[d4 * 4 + 1] = qv.y;
      q[d4 * 4 + 2] = qv.z; q[d4 * 4 + 3] = qv.w;
    }
    const float* wrow = wbuf + ((size_t)(b * NSEL + i) * NHEAD + h) * 32;
    float w0[15], w1[15];
    #pragma unroll
    for (int f = 0; f < 15; ++f) {
      w0[f] = wrow[f] * (1.0f / 255.0f);        // u8 scale folded in
      w1[f] = wrow[15 + f] * (1.0f / 255.0f);
    }
    const uint4* kb4 = (const uint4*)kbT + (size_t)(b * 4 + h) * 4 * 512;
    const uint4* vb4 = (const uint4*)vT + (size_t)(b * 4 + h) * 4 * 512;
    float lg[8];
    #pragma unroll
    for (int u = 0; u < 8; ++u) {
      int j = u * 64 + ln;
      float cacc = 0.f;
      #pragma unroll
      for (int dp = 0; dp < 4; ++dp) {
        uint4 kv = kb4[dp * 512 + j];
        cacc += q[dp * 8 + 0] * BFL(kv.x) + q[dp * 8 + 1] * BFH(kv.x)
              + q[dp * 8 + 2] * BFL(kv.y) + q[dp * 8 + 3] * BFH(kv.y)
              + q[dp * 8 + 4] * BFL(kv.z) + q[dp * 8 + 5] * BFH(kv.z)
              + q[dp * 8 + 6] * BFL(kv.w) + q[dp * 8 + 7] * BFH(kv.w);
      }
      float r0 = 0.f, r1 = 0.f;
      float2 e7 = es2[7 * 512 + j];
      #pragma unroll
      for (int f2 = 0; f2 < 7; ++f2) {
        float2 ee = es2[f2 * 512 + j];
        r0 += ee.x * w0[2 * f2] + ee.y * w0[2 * f2 + 1];
        r1 += ee.x * w1[2 * f2] + ee.y * w1[2 * f2 + 1];
      }
      r0 += e7.x * w0[14];
      r1 += e7.x * w1[14];
      lg[u] = cacc + r0 + e7.y * r1;
    }
    // full-row softmax across the wave (512 logits, 8/lane), in registers
    float m = lg[0];
    #pragma unroll
    for (int u = 1; u < 8; ++u) m = fmaxf(m, lg[u]);
    #pragma unroll
    for (int s = 1; s < 64; s <<= 1) m = fmaxf(m, __shfl_xor(m, s));
    float ssum = 0.f;
    #pragma unroll
    for (int u = 0; u < 8; ++u) { lg[u] = __expf(lg[u] - m); ssum += lg[u]; }
    #pragma unroll
    for (int s = 1; s < 64; s <<= 1) ssum += __shfl_xor(ssum, s);
    float invs = 1.0f / ssum;
    // PV: p in registers, v coalesced; reduced-shuffle epilogue -> LDS obs
    #pragma unroll
    for (int dp = 0; dp < 4; ++dp) {
      float acc[8] = {0.f, 0.f, 0.f, 0.f, 0.f, 0.f, 0.f, 0.f};
      #pragma unroll
      for (int u = 0; u < 8; ++u) {
        uint4 vv = vb4[dp * 512 + u * 64 + ln];
        float p = lg[u];
        acc[0] += p * BFL(vv.x); acc[1] += p * BFH(vv.x);
        acc[2] += p * BFL(vv.y); acc[3] += p * BFH(vv.y);
        acc[4] += p * BFL(vv.z); acc[5] += p * BFH(vv.z);
        acc[6] += p * BFL(vv.w); acc[7] += p * BFH(vv.w);
      }
      #pragma unroll
      for (int s = 1; s < 8; s <<= 1) {
        #pragma unroll
        for (int t = 0; t < 8; ++t) acc[t] += __shfl_xor(acc[t], s);
      }
      int sel = ln & 7;
      float y = acc[0];
      #pragma unroll
      for (int t = 1; t < 8; ++t) y = (sel == t) ? acc[t] : y;
      #pragma unroll
      for (int s = 8; s < 64; s <<= 1) y += __shfl_xor(y, s);
      if (ln < 8) obs[h * DKD + dp * 8 + ln] = y * invs;
    }
  }
  __syncthreads();
  // ---- proj + residual + LN2 + MLP + residual ----
  int c = tid & 31, seg = tid >> 5;
  {
    const float* wo = Wo + (size_t)layer * HDD * CCH + c;
    float pacc = 0.f;
    #pragma unroll
    for (int k = 0; k < 16; ++k) {
      int kk = seg * 16 + k;
      pacc += obs[kk] * wo[kk * CCH];
    }
    part[seg][c] = pacc;
  }
  __syncthreads();
  if (tid < 32) {
    float s = bo[layer * CCH + tid] + emb[(size_t)bid * CCH + tid];
    #pragma unroll
    for (int sg = 0; sg < 8; ++sg) s += part[sg][tid];
    res[tid] = s;
  }
  __syncthreads();
  if (tid < 32) {
    float mu = 0.f, s2 = 0.f;
    #pragma unroll
    for (int c2 = 0; c2 < 32; ++c2) { float v = res[c2]; mu += v; s2 += v * v; }
    mu *= (1.0f / 32.0f);
    float var = s2 * (1.0f / 32.0f) - mu * mu;
    float rstd = rsqrtf(var + 1e-5f);
    hln[tid] = (res[tid] - mu) * rstd * ln2_g[layer * CCH + tid] + ln2_b[layer * CCH + tid];
  }
  __syncthreads();
  {
    const float* w1 = W1 + (size_t)layer * CCH * MLPD;
    float accA = b1[layer * MLPD + tid];
    float accB = b1[layer * MLPD + tid + 256];
    for (int c2 = 0; c2 < 32; ++c2) {
      float hv = hln[c2];
      accA += hv * w1[c2 * MLPD + tid];
      accB += hv * w1[c2 * MLPD + tid + 256];
    }
    a1s[tid]       = 0.5f * accA * (1.0f + erff(accA * 0.70710678118654752f));
    a1s[tid + 256] = 0.5f * accB * (1.0f + erff(accB * 0.70710678118654752f));
  }
  __syncthreads();
  {
    const float* w2 = W2 + (size_t)layer * MLPD * CCH;
    float acc2 = 0.f;
    #pragma unroll 4
    for (int mi = 0; mi < 64; ++mi) {
      int m = seg * 64 + mi;
      acc2 += a1s[m] * w2[m * CCH + c];
    }
    __syncthreads();                    // part[] reuse
    part[seg][c] = acc2;
  }
  __syncthreads();
  if (tid < 32) {
    float s = b2[layer * CCH + tid] + res[tid];
    #pragma unroll
    for (int sg = 0; sg < 8; ++sg) s += part[sg][tid];
    fin[tid] = s;
    if (layer < 3) emb[(size_t)bid * CCH + tid] = s;
  }
  __syncthreads();
  if (layer == 3) {
    if (tid < 32) out[((size_t)b * CCH + tid) * SEQL + pos] = fin[tid];
    return;
  }
  // ---- qkv for layer l+1 (into the ping-pong "next" buffers) ----
  const int l1 = layer + 1;
  bool act = tid < 128;
  int hd = tid & 127;
  int hh2 = hd >> 5, dd2 = hd & 31;
  if (act) {
    float hx[32];
    float mu = 0.f;
    #pragma unroll
    for (int c2 = 0; c2 < 32; ++c2) { hx[c2] = fin[c2]; mu += hx[c2]; }
    mu *= (1.0f / 32.0f);
    float var = 0.f;
    #pragma unroll
    for (int c2 = 0; c2 < 32; ++c2) { float dd = hx[c2] - mu; var += dd * dd; }
    var *= (1.0f / 32.0f);
    float rstd = rsqrtf(var + 1e-5f);
    const float* g = ln1_g + l1 * CCH;
    const float* bb = ln1_b + l1 * CCH;
    #pragma unroll
    for (int c2 = 0; c2 < 32; ++c2) hx[c2] = (hx[c2] - mu) * rstd * g[c2] + bb[c2];
    const float* wq = Wq + (size_t)l1 * CCH * HDD + hd;
    const float* wk = Wk + (size_t)l1 * CCH * HDD + hd;
    const float* wv = Wv + (size_t)l1 * CCH * HDD + hd;
    float q = 0.f, kk = 0.f, vv = 0.f;
    #pragma unroll
    for (int c2 = 0; c2 < 32; ++c2) {
      q += hx[c2] * wq[c2 * HDD];
      kk += hx[c2] * wk[c2 * HDD];
      vv += hx[c2] * wv[c2 * HDD];
    }
    q *= 0.17677669529663687f;
    qs[hd] = q;
    qcN[(size_t)bid * HDD + hd] = q + rcb[(l1 * NHEAD + hh2) * DKD + dd2];
    size_t tpos = ((size_t)(b * 4 + hh2) * 4 + (dd2 >> 3)) * 4096 + (size_t)i * 8 + (dd2 & 7);
    kbTN[tpos] = f2bf(kk);
    vTN[tpos]  = f2bf(vv);
  }
  __syncthreads();
  if (act && hd < 120) {
    int h2 = hd / 30, f = hd % 30;
    const float* rp = rpb + (l1 * NHEAD + h2) * DKD;
    const float* wr = Wrel + ((size_t)l1 * 30 + f) * HDD + h2 * DKD;
    const float* qsh = qs + h2 * DKD;
    float acc = 0.f;
    #pragma unroll
    for (int dd = 0; dd < 32; ++dd) acc += (qsh[dd] + rp[dd]) * wr[dd];
    wbN[((size_t)bid * NHEAD + h2) * 32 + f] = acc;
  }
}

extern "C" void kernel_launch(void* const* d_in, const int* in_sizes, int n_in,
                              void* d_out, int out_size, void* d_ws, size_t ws_size,
                              hipStream_t stream) {
  (void)in_sizes; (void)n_in; (void)ws_size; (void)out_size;
  const float* x_skip    = (const float*)d_in[0];
  const float* attention = (const float*)d_in[1];
  const float* ln1_g = (const float*)d_in[2];
  const float* ln1_b = (const float*)d_in[3];
  const float* Wq    = (const float*)d_in[4];
  const float* Wk    = (const float*)d_in[5];
  const float* Wv    = (const float*)d_in[6];
  const float* Wrel  = (const float*)d_in[7];
  const float* rcb   = (const float*)d_in[8];
  const float* rpb   = (const float*)d_in[9];
  const float* Wo    = (const float*)d_in[10];
  const float* bo    = (const float*)d_in[11];
  const float* ln2_g = (const float*)d_in[12];
  const float* ln2_b = (const float*)d_in[13];
  const float* W1    = (const float*)d_in[14];
  const float* b1    = (const float*)d_in[15];
  const float* W2    = (const float*)d_in[16];
  const float* b2    = (const float*)d_in[17];
  float* out = (float*)d_out;
  char* ws = (char*)d_ws;

  unsigned char* E = (unsigned char*)(ws + 0);        // 45000*16 = 720,000
  int*      idx   = (int*)(ws + 1441792);             // 4,096
  float*    emb   = (float*)(ws + 1445888);           // 131,072
  float*    qcA   = (float*)(ws + 1576960);           // 524,288
  unsigned short* kbTA = (unsigned short*)(ws + 2101248); // 262,144
  unsigned short* vTA  = (unsigned short*)(ws + 2363392); // 262,144
  float*    wbA   = (float*)(ws + 2625536);           // 524,288
  unsigned short* kbTB = (unsigned short*)(ws + 3149824); // 262,144
  unsigned short* vTB  = (unsigned short*)(ws + 3411968); // 262,144
  unsigned* chsel = (unsigned*)(ws + 4788256);        // 4,096 -> ends 4,792,352
  float*    qcB   = (float*)(ws + 4792352);           // 524,288
  float*    wbB   = (float*)(ws + 5316640);           // 524,288 -> ends 5,840,928

  prep_kernel<<<ETB + 128, 256, 0, stream>>>(attention ? E : E, out);  // E build + out zero
  // (attention unused in prep now; kept signature minimal)
  topk_channel_kernel<<<4, 1024, 0, stream>>>(attention, chsel);
  topk_merge_kernel<<<2, 512, 0, stream>>>(chsel, idx);
  gqkv0_kernel<<<1024, 128, 0, stream>>>(x_skip, idx, ln1_g, ln1_b, Wq, Wk, Wv,
                                         Wrel, rcb, rpb, emb, qcA, kbTA, vTA, wbA);
  for (int l = 0; l < 4; ++l) {
    const float* qcI = (l & 1) ? qcB : qcA;
    const unsigned short* kbI = (l & 1) ? kbTB : kbTA;
    const unsigned short* vI  = (l & 1) ? vTB : vTA;
    const float* wbI = (l & 1) ? wbB : wbA;
    float* qcO = (l & 1) ? qcA : qcB;
    unsigned short* kbO = (l & 1) ? kbTA : kbTB;
    unsigned short* vO  = (l & 1) ? vTA : vTB;
    float* wbO = (l & 1) ? wbA : wbB;
    layer_kernel<<<1024, 256, 0, stream>>>(qcI, kbI, vI, wbI, E, idx,
                                           Wo, bo, ln2_g, ln2_b, W1, b1, W2, b2,
                                           ln1_g, ln1_b, Wq, Wk, Wv, Wrel, rcb,
                                           rpb, emb, qcO, kbO, vO, wbO, out, l);
  }
}

// Round 11
// 281.604 us; speedup vs baseline: 1.8830x; 1.0675x over previous
//
#include <hip/hip_runtime.h>
#include <math.h>

#define SEQL   45000
#define NBAT   2
#define CCH    32
#define NSEL   512
#define NHEAD  4
#define DKD    32
#define HDD    128
#define MLPD   512
#define CDCAP  2048
#define NSLICE 32     // histogram/collect slices per channel
#define ETB    176    // etab blocks = ceil(45000/256)

// bf16 helpers: round-to-nearest-even pack, cheap unpack (<<16)
__device__ __forceinline__ unsigned short f2bf(float x) {
  unsigned u = __float_as_uint(x);
  u = (u + 0x7fffu + ((u >> 16) & 1u)) >> 16;
  return (unsigned short)u;
}
#define BFL(u) __uint_as_float((u) << 16)
#define BFH(u) __uint_as_float((u) & 0xffff0000u)
#define U8F(w, s) ((float)(((w) >> (s)) & 0xffu))

// ---------------- K0: etab (u8) + out zero + PARALLEL top-byte hist ---------
// R23: R22's serial 4-block topk was 52us @ 0.6% occupancy (R16 lesson
// re-learned: front-end kernels are latency-bound; parallelism > work).
// Slice hist restored: 128 blocks, LDS-local 256-bin, 256 global atomics each.
__global__ __launch_bounds__(256) void prep_kernel(const float* __restrict__ att,
                                                   unsigned char* __restrict__ E,
                                                   int* __restrict__ ghist1,
                                                   float* __restrict__ out) {
  __shared__ int lh[256];
  {
    int nthr = gridDim.x * 256;
    int gt = blockIdx.x * 256 + threadIdx.x;
    float4 z4 = make_float4(0.f, 0.f, 0.f, 0.f);
    float4* o4 = (float4*)out;
    for (int i = gt; i < NBAT * CCH * SEQL / 4; i += nthr) o4[i] = z4;
  }
  if (blockIdx.x < ETB) {
    int a = blockIdx.x * 256 + threadIdx.x;
    if (a >= SEQL) return;
    float ad = (float)a;
    float outv[16];
    float log2S = log2f((float)SEQL);
    #pragma unroll
    for (int k = 0; k < 5; ++k) {
      float hl = exp2f(3.0f + (float)k * (log2S - 3.0f) * 0.25f);
      outv[k] = exp2f(-ad / hl);
    }
    const int cw[5] = {1, 3, 7, 15, 31};
    #pragma unroll
    for (int k = 0; k < 5; ++k) outv[5 + k] = (a < cw[k]) ? 1.0f : 0.0f;
    float pmax = 0.0f;
    float pk[5];
    #pragma unroll
    for (int k = 0; k < 5; ++k) {
      float mean = 9000.0f * (float)(k + 1);
      float sd = 4500.0f;
      float cc = (mean / sd) * (mean / sd);      // 4,16,36,64,100
      float rr = mean / (sd * sd);
      float logz = lgammaf(cc) - cc * logf(rr);
      float pp;
      if (a == 0) pp = 1e-8f;                    // xlogy -> -inf -> exp = 0
      else pp = expf((cc - 1.0f) * logf(ad) - rr * ad - logz) + 1e-8f;
      pk[k] = pp;
      float mstar = (cc - 1.0f) / rr;            // 6750..44550, interior mode
      float m0 = floorf(mstar), m1 = m0 + 1.0f;
      if (m1 > (float)(SEQL - 1)) m1 = (float)(SEQL - 1);
      float p0 = expf((cc - 1.0f) * logf(m0) - rr * m0 - logz) + 1e-8f;
      float p1 = expf((cc - 1.0f) * logf(m1) - rr * m1 - logz) + 1e-8f;
      pmax = fmaxf(pmax, fmaxf(p0, p1));
    }
    #pragma unroll
    for (int k = 0; k < 5; ++k) outv[10 + k] = pk[k] / pmax;
    outv[15] = 0.0f;
    unsigned by[16];
    #pragma unroll
    for (int k = 0; k < 15; ++k)
      by[k] = (unsigned)(fminf(fmaxf(outv[k], 0.f), 1.f) * 255.f + 0.5f);
    by[15] = 0u;
    uint4 o;
    o.x = by[0]  | (by[1]  << 8) | (by[2]  << 16) | (by[3]  << 24);
    o.y = by[4]  | (by[5]  << 8) | (by[6]  << 16) | (by[7]  << 24);
    o.z = by[8]  | (by[9]  << 8) | (by[10] << 16) | (by[11] << 24);
    o.w = by[12] | (by[13] << 8) | (by[14] << 16);
    *(uint4*)(E + (size_t)a * 16) = o;
  } else {
    int bid = blockIdx.x - ETB;       // 0..127
    int ch4 = bid >> 5, blk = bid & 31;
    int b = ch4 >> 1, ch = ch4 & 1;
    const float* row = att + ((size_t)b * 3 + 1 + ch) * SEQL;
    int t = threadIdx.x;
    lh[t] = 0;
    __syncthreads();
    int per = (SEQL + NSLICE - 1) / NSLICE;
    int lo = blk * per;
    int hi = lo + per; if (hi > SEQL) hi = SEQL;
    for (int i = lo + t; i < hi; i += 256)
      atomicAdd(&lh[__float_as_uint(row[i]) >> 24], 1);   // vals>=0 monotone
    __syncthreads();
    if (lh[t]) atomicAdd(&ghist1[ch4 * 256 + t], lh[t]);
  }
}

// ---------------- K1a: second-byte hist (parallel slices) -------------------
__global__ __launch_bounds__(256) void topk_hist2_kernel(
    const float* __restrict__ att, const int* __restrict__ ghist1,
    int* __restrict__ ghist2) {
  __shared__ int scan[256];
  __shared__ int lh[256];
  __shared__ int auxB;
  int bid = blockIdx.x;             // 0..127
  int ch4 = bid >> 5, blk = bid & 31;
  int b = ch4 >> 1, ch = ch4 & 1;
  const float* row = att + ((size_t)b * 3 + 1 + ch) * SEQL;
  int t = threadIdx.x;
  scan[t] = ghist1[ch4 * 256 + t];
  __syncthreads();
  for (int d = 1; d < 256; d <<= 1) {
    int v = scan[t] + ((t + d < 256) ? scan[t + d] : 0);
    __syncthreads();
    scan[t] = v;
    __syncthreads();
  }
  {
    int sufEx = (t == 255) ? 0 : scan[t + 1];
    if (scan[t] >= 256 && sufEx < 256) auxB = t;
  }
  __syncthreads();
  int B = auxB;
  lh[t] = 0;
  __syncthreads();
  int per = (SEQL + NSLICE - 1) / NSLICE;
  int lo = blk * per;
  int hi = lo + per; if (hi > SEQL) hi = SEQL;
  for (int i = lo + t; i < hi; i += 256) {
    unsigned key = __float_as_uint(row[i]);
    if ((int)(key >> 24) == B) atomicAdd(&lh[(key >> 16) & 0xffu], 1);
  }
  __syncthreads();
  if (lh[t]) atomicAdd(&ghist2[ch4 * 256 + t], lh[t]);
}

// ---------------- K1b: collect (parallel slices, ballot atomics) ------------
__global__ __launch_bounds__(256) void topk_collect_kernel(
    const float* __restrict__ att, const int* __restrict__ ghist1,
    const int* __restrict__ ghist2, unsigned long long* __restrict__ cand,
    int* __restrict__ cnt) {
  __shared__ int scan[256];
  __shared__ int aux[2];
  int bid = blockIdx.x;             // 0..127
  int ch4 = bid >> 5, blk = bid & 31;
  int b = ch4 >> 1, ch = ch4 & 1;
  const float* row = att + ((size_t)b * 3 + 1 + ch) * SEQL;
  int t = threadIdx.x;
  // level-1 scan -> B, want
  scan[t] = ghist1[ch4 * 256 + t];
  __syncthreads();
  for (int d = 1; d < 256; d <<= 1) {
    int v = scan[t] + ((t + d < 256) ? scan[t + d] : 0);
    __syncthreads();
    scan[t] = v;
    __syncthreads();
  }
  {
    int sufEx = (t == 255) ? 0 : scan[t + 1];
    if (scan[t] >= 256 && sufEx < 256) { aux[0] = t; aux[1] = 256 - sufEx; }
  }
  __syncthreads();
  int B = aux[0], want = aux[1];
  // level-2 scan -> T16
  scan[t] = ghist2[ch4 * 256 + t];
  __syncthreads();
  for (int d = 1; d < 256; d <<= 1) {
    int v = scan[t] + ((t + d < 256) ? scan[t + d] : 0);
    __syncthreads();
    scan[t] = v;
    __syncthreads();
  }
  {
    int sufEx = (t == 255) ? 0 : scan[t + 1];
    if (scan[t] >= want && sufEx < want) aux[0] = (B << 8) | t;
  }
  __syncthreads();
  unsigned T16 = (unsigned)aux[0];
  int per = (SEQL + NSLICE - 1) / NSLICE;
  int lo = blk * per;
  int hi = lo + per; if (hi > SEQL) hi = SEQL;
  int lane = t & 63;
  for (int base = lo; base < hi; base += 256) {
    int i = base + t;
    bool pass = false; unsigned key = 0;
    if (i < hi) {
      key = __float_as_uint(row[i]);
      pass = (key >> 16) >= T16;
    }
    unsigned long long mask = __ballot(pass);
    if (mask) {
      int np = __popcll(mask);
      int lead = __ffsll((long long)mask) - 1;
      int pbase = 0;
      if (lane == lead) pbase = atomicAdd(&cnt[ch4], np);
      pbase = __shfl(pbase, lead);
      if (pass) {
        int off = __popcll(mask & ((1ull << lane) - 1ull));
        int p = pbase + off;
        if (p < CDCAP)
          cand[(size_t)ch4 * CDCAP + p] =
              ((unsigned long long)key << 32) | (unsigned)(~(unsigned)i);
      }
    }
  }
}

// ---------------- K2a: per-channel desc sort -> top-256 (4 parallel blocks) -
__global__ __launch_bounds__(1024) void topk_sort_kernel(
    const unsigned long long* __restrict__ cand, const int* __restrict__ cnt,
    unsigned* __restrict__ chsel) {
  __shared__ unsigned long long sc[CDCAP];
  int ch4 = blockIdx.x, t = threadIdx.x;
  int n = cnt[ch4]; if (n > CDCAP) n = CDCAP;   // >=256 by construction
  int P = 256;
  while (P < n) P <<= 1;                        // typical 512
  for (int i = t; i < P; i += 1024)
    sc[i] = (i < n) ? cand[(size_t)ch4 * CDCAP + i] : 0ull;  // 0 sorts last
  __syncthreads();
  for (int k = 2; k <= P; k <<= 1) {
    for (int j = k >> 1; j > 0; j >>= 1) {
      for (int i = t; i < P; i += 1024) {
        int ixj = i ^ j;
        if (ixj > i) {
          unsigned long long va = sc[i], vb2 = sc[ixj];
          bool up = ((i & k) == 0);
          if ((va < vb2) == up) { sc[i] = vb2; sc[ixj] = va; }
        }
      }
      __syncthreads();
    }
  }
  // desc u64 = value desc, tie -> larger ~i = smaller index first
  if (t < 256)
    chsel[(size_t)ch4 * 256 + t] = ~(unsigned)(sc[t] & 0xFFFFFFFFull);
}

// ---------------- K2b: merge acc+don, ascending sort of 512 -----------------
__global__ __launch_bounds__(512) void topk_merge_kernel(const unsigned* __restrict__ chsel,
                                                         int* __restrict__ idx) {
  __shared__ int m[512];
  int b = blockIdx.x, tid = threadIdx.x;
  m[tid] = (int)chsel[(size_t)b * 512 + tid];
  __syncthreads();
  for (int k = 2; k <= 512; k <<= 1) {
    for (int j = k >> 1; j > 0; j >>= 1) {
      int ixj = tid ^ j;
      if (ixj > tid) {
        int va = m[tid], vb2 = m[ixj];
        bool up = ((tid & k) == 0);
        if ((va > vb2) == up) { m[tid] = vb2; m[ixj] = va; }
      }
      __syncthreads();
    }
  }
  idx[b * 512 + tid] = m[tid];
}

// ---------------- K3: fused gather + LN1 + QKV layer 0 ----------------------
// kbT/vT layout (bf16): [((b*4+h)*4+dpack)*4096 + i*8 + (d&7)]
__global__ __launch_bounds__(128) void gqkv0_kernel(
    const float* __restrict__ x, const int* __restrict__ idx,
    const float* __restrict__ ln_g, const float* __restrict__ ln_b,
    const float* __restrict__ Wq, const float* __restrict__ Wk,
    const float* __restrict__ Wv, const float* __restrict__ Wrel,
    const float* __restrict__ rcb, const float* __restrict__ rpb,
    float* __restrict__ emb, float* __restrict__ qc,
    unsigned short* __restrict__ kbT, unsigned short* __restrict__ vT,
    float* __restrict__ wb) {
  __shared__ float qs[128];
  const int l = 0;
  int hd = threadIdx.x;        // 0..127
  int hh = hd >> 5, d = hd & 31;
  int row = blockIdx.x;        // b*512 + i
  int b = row >> 9, ii = row & 511;
  int li = idx[b * NSEL + ii];
  float h[32];
  float mu = 0.f;
  #pragma unroll
  for (int c = 0; c < 32; ++c) {
    h[c] = x[((size_t)b * CCH + c) * SEQL + li];
    mu += h[c];
  }
  if (hd < 32) emb[(size_t)row * CCH + hd] = h[hd];
  mu *= (1.0f / 32.0f);
  float var = 0.f;
  #pragma unroll
  for (int c = 0; c < 32; ++c) { float dd0 = h[c] - mu; var += dd0 * dd0; }
  var *= (1.0f / 32.0f);
  float rstd = rsqrtf(var + 1e-5f);
  const float* g = ln_g + l * CCH;
  const float* bb = ln_b + l * CCH;
  #pragma unroll
  for (int c = 0; c < 32; ++c) h[c] = (h[c] - mu) * rstd * g[c] + bb[c];
  const float* wq = Wq + (size_t)l * CCH * HDD + hd;
  const float* wk = Wk + (size_t)l * CCH * HDD + hd;
  const float* wv = Wv + (size_t)l * CCH * HDD + hd;
  float q = 0.f, kk = 0.f, vv = 0.f;
  #pragma unroll
  for (int c = 0; c < 32; ++c) {
    q += h[c] * wq[c * HDD];
    kk += h[c] * wk[c * HDD];
    vv += h[c] * wv[c * HDD];
  }
  q *= 0.17677669529663687f;   // DK^-0.5
  qs[hd] = q;
  qc[(size_t)row * HDD + hd] = q + rcb[(l * NHEAD + hh) * DKD + d];
  size_t tpos = ((size_t)(b * 4 + hh) * 4 + (d >> 3)) * 4096 + (size_t)ii * 8 + (d & 7);
  kbT[tpos] = f2bf(kk);
  vT[tpos]  = f2bf(vv);
  __syncthreads();
  if (hd < 120) {
    int h2 = hd / 30, f = hd % 30;
    const float* wr = Wrel + ((size_t)l * 30 + f) * HDD + h2 * DKD;
    const float* rp = rpb + (l * NHEAD + h2) * DKD;
    const float* qsh = qs + h2 * DKD;
    float acc = 0.f;
    #pragma unroll
    for (int dd = 0; dd < 32; ++dd) acc += (qsh[dd] + rp[dd]) * wr[dd];
    wb[((size_t)row * NHEAD + h2) * 32 + f] = acc;   // padded stride 32
  }
}

// ---------------- K4: fused layer = attn + proj/LN2/MLP + qkv(l+1) ----------
// Measured-best layer body (R15/R16: u8 E decode in-layer, float2 es2 b64
// reads = 41.7us). LDS ~37.2KB -> 4 blocks/CU at (256,4).
__global__ __launch_bounds__(256, 4) void layer_kernel(
    const float* __restrict__ qc, const unsigned short* __restrict__ kbT,
    const unsigned short* __restrict__ vT, const float* __restrict__ wbuf,
    const unsigned char* __restrict__ E, const int* __restrict__ idx,
    const float* __restrict__ Wo, const float* __restrict__ bo,
    const float* __restrict__ ln2_g, const float* __restrict__ ln2_b,
    const float* __restrict__ W1, const float* __restrict__ b1,
    const float* __restrict__ W2, const float* __restrict__ b2,
    const float* __restrict__ ln1_g, const float* __restrict__ ln1_b,
    const float* __restrict__ Wq, const float* __restrict__ Wk,
    const float* __restrict__ Wv, const float* __restrict__ Wrel,
    const float* __restrict__ rcb, const float* __restrict__ rpb,
    float* __restrict__ emb, float* __restrict__ qcN,
    unsigned short* __restrict__ kbTN, unsigned short* __restrict__ vTN,
    float* __restrict__ wbN, float* __restrict__ out, int layer) {
  __shared__ float2 es2[8 * 512]; // 32KB: es2[f2*512+j] = feats {2f2,2f2+1}; [7].y = sign
  __shared__ float obs[128];      // attn output row (LDS-resident)
  __shared__ float part[8][32];
  __shared__ float res[32];
  __shared__ float hln[32];
  __shared__ float fin[32];
  __shared__ float a1s[MLPD];
  __shared__ float qs[128];
  int bid = blockIdx.x;
  int b = bid >> 9;
  int i = bid & 511;
  int tid = threadIdx.x;
  int pos = idx[b * NSEL + i];     // this row's sequence position
  // ---- E-row decode once per block into LDS (head-shared) ----
  #pragma unroll
  for (int rep = 0; rep < 2; ++rep) {
    int j = tid + rep * 256;
    int dj = pos - idx[b * NSEL + j];
    int a = dj < 0 ? -dj : dj;
    uint4 e = *(const uint4*)(E + (size_t)a * 16);    // one 16B gather/pair
    float sgn = dj > 0 ? 1.f : (dj < 0 ? -1.f : 0.f);
    es2[0 * 512 + j] = make_float2(U8F(e.x, 0),  U8F(e.x, 8));
    es2[1 * 512 + j] = make_float2(U8F(e.x, 16), U8F(e.x, 24));
    es2[2 * 512 + j] = make_float2(U8F(e.y, 0),  U8F(e.y, 8));
    es2[3 * 512 + j] = make_float2(U8F(e.y, 16), U8F(e.y, 24));
    es2[4 * 512 + j] = make_float2(U8F(e.z, 0),  U8F(e.z, 8));
    es2[5 * 512 + j] = make_float2(U8F(e.z, 16), U8F(e.z, 24));
    es2[6 * 512 + j] = make_float2(U8F(e.w, 0),  U8F(e.w, 8));
    es2[7 * 512 + j] = make_float2(U8F(e.w, 16), sgn);
  }
  __syncthreads();
  // ---- attention: wave = head ----
  {
    int h = tid >> 6, ln = tid & 63;
    const float* qrow = qc + (size_t)(b * NSEL + i) * HDD + h * DKD;
    float q[32];
    #pragma unroll
    for (int d4 = 0; d4 < 8; ++d4) {
      float4 qv = *(const float4*)(qrow + d4 * 4);
      q[d4 * 4 + 0] = qv.x; q[d4 * 4 + 1] = qv.y;
      q[d4 * 4 + 2] = qv.z; q[d4 * 4 + 3] = qv.w;
    }
    const float* wrow = wbuf + ((size_t)(b * NSEL + i) * NHEAD + h) * 32;
    float w0[15], w1[15];
    #pragma unroll
    for (int f = 0; f < 15; ++f) {
      w0[f] = wrow[f] * (1.0f / 255.0f);        // u8 scale folded in
      w1[f] = wrow[15 + f] * (1.0f / 255.0f);
    }
    const uint4* kb4 = (const uint4*)kbT + (size_t)(b * 4 + h) * 4 * 512;
    const uint4* vb4 = (const uint4*)vT + (size_t)(b * 4 + h) * 4 * 512;
    float lg[8];
    #pragma unroll
    for (int u = 0; u < 8; ++u) {
      int j = u * 64 + ln;
      float cacc = 0.f;
      #pragma unroll
      for (int dp = 0; dp < 4; ++dp) {
        uint4 kv = kb4[dp * 512 + j];
        cacc += q[dp * 8 + 0] * BFL(kv.x) + q[dp * 8 + 1] * BFH(kv.x)
              + q[dp * 8 + 2] * BFL(kv.y) + q[dp * 8 + 3] * BFH(kv.y)
              + q[dp * 8 + 4] * BFL(kv.z) + q[dp * 8 + 5] * BFH(kv.z)
              + q[dp * 8 + 6] * BFL(kv.w) + q[dp * 8 + 7] * BFH(kv.w);
      }
      float r0 = 0.f, r1 = 0.f;
      float2 e7 = es2[7 * 512 + j];
      #pragma unroll
      for (int f2 = 0; f2 < 7; ++f2) {
        float2 ee = es2[f2 * 512 + j];
        r0 += ee.x * w0[2 * f2] + ee.y * w0[2 * f2 + 1];
        r1 += ee.x * w1[2 * f2] + ee.y * w1[2 * f2 + 1];
      }
      r0 += e7.x * w0[14];
      r1 += e7.x * w1[14];
      lg[u] = cacc + r0 + e7.y * r1;
    }
    // full-row softmax across the wave (512 logits, 8/lane), in registers
    float m = lg[0];
    #pragma unroll
    for (int u = 1; u < 8; ++u) m = fmaxf(m, lg[u]);
    #pragma unroll
    for (int s = 1; s < 64; s <<= 1) m = fmaxf(m, __shfl_xor(m, s));
    float ssum = 0.f;
    #pragma unroll
    for (int u = 0; u < 8; ++u) { lg[u] = __expf(lg[u] - m); ssum += lg[u]; }
    #pragma unroll
    for (int s = 1; s < 64; s <<= 1) ssum += __shfl_xor(ssum, s);
    float invs = 1.0f / ssum;
    // PV: p in registers, v coalesced; reduced-shuffle epilogue -> LDS obs
    #pragma unroll
    for (int dp = 0; dp < 4; ++dp) {
      float acc[8] = {0.f, 0.f, 0.f, 0.f, 0.f, 0.f, 0.f, 0.f};
      #pragma unroll
      for (int u = 0; u < 8; ++u) {
        uint4 vv = vb4[dp * 512 + u * 64 + ln];
        float p = lg[u];
        acc[0] += p * BFL(vv.x); acc[1] += p * BFH(vv.x);
        acc[2] += p * BFL(vv.y); acc[3] += p * BFH(vv.y);
        acc[4] += p * BFL(vv.z); acc[5] += p * BFH(vv.z);
        acc[6] += p * BFL(vv.w); acc[7] += p * BFH(vv.w);
      }
      #pragma unroll
      for (int s = 1; s < 8; s <<= 1) {
        #pragma unroll
        for (int t = 0; t < 8; ++t) acc[t] += __shfl_xor(acc[t], s);
      }
      int sel = ln & 7;
      float y = acc[0];
      #pragma unroll
      for (int t = 1; t < 8; ++t) y = (sel == t) ? acc[t] : y;
      #pragma unroll
      for (int s = 8; s < 64; s <<= 1) y += __shfl_xor(y, s);
      if (ln < 8) obs[h * DKD + dp * 8 + ln] = y * invs;
    }
  }
  __syncthreads();
  // ---- proj + residual + LN2 + MLP + residual ----
  int c = tid & 31, seg = tid >> 5;
  {
    const float* wo = Wo + (size_t)layer * HDD * CCH + c;
    float pacc = 0.f;
    #pragma unroll
    for (int k = 0; k < 16; ++k) {
      int kk = seg * 16 + k;
      pacc += obs[kk] * wo[kk * CCH];
    }
    part[seg][c] = pacc;
  }
  __syncthreads();
  if (tid < 32) {
    float s = bo[layer * CCH + tid] + emb[(size_t)bid * CCH + tid];
    #pragma unroll
    for (int sg = 0; sg < 8; ++sg) s += part[sg][tid];
    res[tid] = s;
  }
  __syncthreads();
  if (tid < 32) {
    float mu = 0.f, s2 = 0.f;
    #pragma unroll
    for (int c2 = 0; c2 < 32; ++c2) { float v = res[c2]; mu += v; s2 += v * v; }
    mu *= (1.0f / 32.0f);
    float var = s2 * (1.0f / 32.0f) - mu * mu;
    float rstd = rsqrtf(var + 1e-5f);
    hln[tid] = (res[tid] - mu) * rstd * ln2_g[layer * CCH + tid] + ln2_b[layer * CCH + tid];
  }
  __syncthreads();
  {
    const float* w1 = W1 + (size_t)layer * CCH * MLPD;
    float accA = b1[layer * MLPD + tid];
    float accB = b1[layer * MLPD + tid + 256];
    for (int c2 = 0; c2 < 32; ++c2) {
      float hv = hln[c2];
      accA += hv * w1[c2 * MLPD + tid];
      accB += hv * w1[c2 * MLPD + tid + 256];
    }
    a1s[tid]       = 0.5f * accA * (1.0f + erff(accA * 0.70710678118654752f));
    a1s[tid + 256] = 0.5f * accB * (1.0f + erff(accB * 0.70710678118654752f));
  }
  __syncthreads();
  {
    const float* w2 = W2 + (size_t)layer * MLPD * CCH;
    float acc2 = 0.f;
    #pragma unroll 4
    for (int mi = 0; mi < 64; ++mi) {
      int m = seg * 64 + mi;
      acc2 += a1s[m] * w2[m * CCH + c];
    }
    __syncthreads();                    // part[] reuse
    part[seg][c] = acc2;
  }
  __syncthreads();
  if (tid < 32) {
    float s = b2[layer * CCH + tid] + res[tid];
    #pragma unroll
    for (int sg = 0; sg < 8; ++sg) s += part[sg][tid];
    fin[tid] = s;
    if (layer < 3) emb[(size_t)bid * CCH + tid] = s;
  }
  __syncthreads();
  if (layer == 3) {
    if (tid < 32) out[((size_t)b * CCH + tid) * SEQL + pos] = fin[tid];
    return;
  }
  // ---- qkv for layer l+1 (into the ping-pong "next" buffers) ----
  const int l1 = layer + 1;
  bool act = tid < 128;
  int hd = tid & 127;
  int hh2 = hd >> 5, dd2 = hd & 31;
  if (act) {
    float hx[32];
    float mu = 0.f;
    #pragma unroll
    for (int c2 = 0; c2 < 32; ++c2) { hx[c2] = fin[c2]; mu += hx[c2]; }
    mu *= (1.0f / 32.0f);
    float var = 0.f;
    #pragma unroll
    for (int c2 = 0; c2 < 32; ++c2) { float dd = hx[c2] - mu; var += dd * dd; }
    var *= (1.0f / 32.0f);
    float rstd = rsqrtf(var + 1e-5f);
    const float* g = ln1_g + l1 * CCH;
    const float* bb = ln1_b + l1 * CCH;
    #pragma unroll
    for (int c2 = 0; c2 < 32; ++c2) hx[c2] = (hx[c2] - mu) * rstd * g[c2] + bb[c2];
    const float* wq = Wq + (size_t)l1 * CCH * HDD + hd;
    const float* wk = Wk + (size_t)l1 * CCH * HDD + hd;
    const float* wv = Wv + (size_t)l1 * CCH * HDD + hd;
    float q = 0.f, kk = 0.f, vv = 0.f;
    #pragma unroll
    for (int c2 = 0; c2 < 32; ++c2) {
      q += hx[c2] * wq[c2 * HDD];
      kk += hx[c2] * wk[c2 * HDD];
      vv += hx[c2] * wv[c2 * HDD];
    }
    q *= 0.17677669529663687f;
    qs[hd] = q;
    qcN[(size_t)bid * HDD + hd] = q + rcb[(l1 * NHEAD + hh2) * DKD + dd2];
    size_t tpos = ((size_t)(b * 4 + hh2) * 4 + (dd2 >> 3)) * 4096 + (size_t)i * 8 + (dd2 & 7);
    kbTN[tpos] = f2bf(kk);
    vTN[tpos]  = f2bf(vv);
  }
  __syncthreads();
  if (act && hd < 120) {
    int h2 = hd / 30, f = hd % 30;
    const float* rp = rpb + (l1 * NHEAD + h2) * DKD;
    const float* wr = Wrel + ((size_t)l1 * 30 + f) * HDD + h2 * DKD;
    const float* qsh = qs + h2 * DKD;
    float acc = 0.f;
    #pragma unroll
    for (int dd = 0; dd < 32; ++dd) acc += (qsh[dd] + rp[dd]) * wr[dd];
    wbN[((size_t)bid * NHEAD + h2) * 32 + f] = acc;
  }
}

extern "C" void kernel_launch(void* const* d_in, const int* in_sizes, int n_in,
                              void* d_out, int out_size, void* d_ws, size_t ws_size,
                              hipStream_t stream) {
  (void)in_sizes; (void)n_in; (void)ws_size; (void)out_size;
  const float* x_skip    = (const float*)d_in[0];
  const float* attention = (const float*)d_in[1];
  const float* ln1_g = (const float*)d_in[2];
  const float* ln1_b = (const float*)d_in[3];
  const float* Wq    = (const float*)d_in[4];
  const float* Wk    = (const float*)d_in[5];
  const float* Wv    = (const float*)d_in[6];
  const float* Wrel  = (const float*)d_in[7];
  const float* rcb   = (const float*)d_in[8];
  const float* rpb   = (const float*)d_in[9];
  const float* Wo    = (const float*)d_in[10];
  const float* bo    = (const float*)d_in[11];
  const float* ln2_g = (const float*)d_in[12];
  const float* ln2_b = (const float*)d_in[13];
  const float* W1    = (const float*)d_in[14];
  const float* b1    = (const float*)d_in[15];
  const float* W2    = (const float*)d_in[16];
  const float* b2    = (const float*)d_in[17];
  float* out = (float*)d_out;
  char* ws = (char*)d_ws;

  unsigned char* E = (unsigned char*)(ws + 0);        // 45000*16 = 720,000
  int*      idx   = (int*)(ws + 1441792);             // 4,096
  float*    emb   = (float*)(ws + 1445888);           // 131,072
  float*    qcA   = (float*)(ws + 1576960);           // 524,288
  unsigned short* kbTA = (unsigned short*)(ws + 2101248); // 262,144
  unsigned short* vTA  = (unsigned short*)(ws + 2363392); // 262,144
  float*    wbA   = (float*)(ws + 2625536);           // 524,288
  unsigned short* kbTB = (unsigned short*)(ws + 3149824); // 262,144
  unsigned short* vTB  = (unsigned short*)(ws + 3411968); // 262,144
  int*      ghist1 = (int*)(ws + 3674112);            // 4,096
  int*      ghist2 = (int*)(ws + 3678208);            // 4,096
  int*      cnt    = (int*)(ws + 3682304);            // 16
  unsigned long long* cand = (unsigned long long*)(ws + 4722720); // 65,536
  unsigned* chsel = (unsigned*)(ws + 4788256);        // 4,096 -> ends 4,792,352
  float*    qcB   = (float*)(ws + 4792352);           // 524,288
  float*    wbB   = (float*)(ws + 5316640);           // 524,288 -> ends 5,840,928

  hipMemsetAsync(ws + 3674112, 0, 4096 + 4096 + 32, stream);  // ghist1+ghist2+cnt
  prep_kernel<<<ETB + 128, 256, 0, stream>>>(attention, E, ghist1, out);
  topk_hist2_kernel<<<128, 256, 0, stream>>>(attention, ghist1, ghist2);
  topk_collect_kernel<<<128, 256, 0, stream>>>(attention, ghist1, ghist2, cand, cnt);
  topk_sort_kernel<<<4, 1024, 0, stream>>>(cand, cnt, chsel);
  topk_merge_kernel<<<2, 512, 0, stream>>>(chsel, idx);
  gqkv0_kernel<<<1024, 128, 0, stream>>>(x_skip, idx, ln1_g, ln1_b, Wq, Wk, Wv,
                                         Wrel, rcb, rpb, emb, qcA, kbTA, vTA, wbA);
  for (int l = 0; l < 4; ++l) {
    const float* qcI = (l & 1) ? qcB : qcA;
    const unsigned short* kbI = (l & 1) ? kbTB : kbTA;
    const unsigned short* vI  = (l & 1) ? vTB : vTA;
    const float* wbI = (l & 1) ? wbB : wbA;
    float* qcO = (l & 1) ? qcA : qcB;
    unsigned short* kbO = (l & 1) ? kbTA : kbTB;
    unsigned short* vO  = (l & 1) ? vTA : vTB;
    float* wbO = (l & 1) ? wbA : wbB;
    layer_kernel<<<1024, 256, 0, stream>>>(qcI, kbI, vI, wbI, E, idx,
                                           Wo, bo, ln2_g, ln2_b, W1, b1, W2, b2,
                                           ln1_g, ln1_b, Wq, Wk, Wv, Wrel, rcb,
                                           rpb, emb, qcO, kbO, vO, wbO, out, l);
  }
}